// Round 4
// baseline (403.559 us; speedup 1.0000x reference)
//
#include <hip/hip_runtime.h>
#include <hip/hip_bf16.h>
#include <math.h>

namespace {

constexpr int NTOK   = 4096;   // B*T
constexpr int DDIM   = 1024;
constexpr int E      = 8;
constexpr int HDIM   = 2048;
constexpr int MAXROWS = 8192;  // NTOK * K (every token -> exactly 2 rows)
constexpr int MAXBLK  = 72;    // >= sum_e ceil(cnt_e/128) <= 64+7; 72 = 8*9 (XCD-clean)

typedef __bf16 bf16;
typedef __attribute__((ext_vector_type(4))) __bf16 bf16x4;
typedef __attribute__((ext_vector_type(8))) __bf16 bf16x8;
typedef __attribute__((ext_vector_type(4))) float floatx4;
typedef __attribute__((ext_vector_type(4))) int   i32x4;

// async global->LDS, 16B per lane; LDS dest = WAVE-UNIFORM base, HW adds lane*16
__device__ inline void gload_lds16(const bf16* g, bf16* l) {
  __builtin_amdgcn_global_load_lds(
      (const __attribute__((address_space(1))) void*)g,
      (__attribute__((address_space(3))) void*)l, 16, 0, 0);
}

// inline-asm ds_read_b128: invisible to the waitcnt pass (no conservative vmcnt(0)
// drain of in-flight prefetch). Discipline: explicit lgkmcnt(0) + sched_barrier(0)
// before the consuming MFMAs (rule #18).
__device__ inline bf16x8 ds_read16(const bf16* p) {
  i32x4 r;
  asm volatile("ds_read_b128 %0, %1"
               : "=v"(r)
               : "v"((const __attribute__((address_space(3))) bf16*)p));
  return __builtin_bit_cast(bf16x8, r);
}

// -------- transpose+cast tile body: fp32 src [R][C] -> bf16 dst [C][R] --------
// LDS pad 66 (row stride 132B = 33 banks === 1 mod 32): the 16 scalar column
// reads hit rows 8 apart -> 8 banks apart -> 2-way (free, m136). Old pad 72
// (stride 36 banks === 4) made rows-8-apart collide 8-way.
__device__ inline void transpose_tile(const float* __restrict__ src,
                                      bf16* __restrict__ dst,
                                      int R, int C, int c0, int r0,
                                      bf16 (*tile)[66]) {
  int tid = threadIdx.x;
  int tr = tid >> 4;          // 0..15
  int tc = (tid & 15) * 4;    // 0..60
#pragma unroll
  for (int i = 0; i < 4; ++i) {
    int r = tr + i * 16;
    float4 v = *(const float4*)(src + (size_t)(r0 + r) * C + c0 + tc);
    bf16x4 o;
    o[0] = (bf16)v.x; o[1] = (bf16)v.y; o[2] = (bf16)v.z; o[3] = (bf16)v.w;
    *(bf16x4*)&tile[r][tc] = o;
  }
  __syncthreads();
  int tr2 = tid >> 3;         // 0..31
  int tc2 = (tid & 7) * 8;    // 0..56
#pragma unroll
  for (int i = 0; i < 2; ++i) {
    int c = tr2 + i * 32;
    bf16x8 v;
#pragma unroll
    for (int j = 0; j < 8; ++j) v[j] = tile[tc2 + j][c];
    *(bf16x8*)(dst + (size_t)(c0 + c) * R + r0 + tc2) = v;
  }
}

// ======== prep: ONE launch = W1 transpose + W2 transpose + router (all independent) ========
// blocks [0,4096)      : W1 [E][D][H] fp32 -> W1T [E][H][D] bf16
// blocks [4096,8192)   : W2 [E][H][D] fp32 -> W2T [E][D][H] bf16
// blocks [8192,8704)   : router (logits, top-2, gates, bf16 cast of x). No count
//                        atomics here -- counts are histogrammed in scan_scatter.
__global__ __launch_bounds__(256) void prep_kernel(
    const float* __restrict__ x,  const float* __restrict__ Wr,
    const float* __restrict__ br, const float* __restrict__ W1,
    const float* __restrict__ W2,
    int* __restrict__ topk_e, float* __restrict__ topk_g,
    bf16* __restrict__ xb, bf16* __restrict__ W1T, bf16* __restrict__ W2T) {
  __shared__ bf16 tile[64][66];
  int b = blockIdx.x;
  if (b < 4096) {
    // W1: R=DDIM(1024), C=HDIM(2048); grid (32 c-tiles, 16 r-tiles, 8 experts)
    int bx = b & 31, by = (b >> 5) & 15, bz = b >> 9;
    const float* src = W1 + (size_t)bz * DDIM * HDIM;
    bf16* dst = W1T + (size_t)bz * DDIM * HDIM;
    transpose_tile(src, dst, DDIM, HDIM, bx * 64, by * 64, tile);
    return;
  }
  if (b < 8192) {
    // W2: R=HDIM(2048), C=DDIM(1024); grid (16 c-tiles, 32 r-tiles, 8 experts)
    int lb = b - 4096;
    int bx = lb & 15, by = (lb >> 4) & 31, bz = lb >> 9;
    const float* src = W2 + (size_t)bz * DDIM * HDIM;
    bf16* dst = W2T + (size_t)bz * DDIM * HDIM;
    transpose_tile(src, dst, HDIM, DDIM, bx * 64, by * 64, tile);
    return;
  }
  // ---- router: wave = 2 tokens; lane l owns channels d = l + 64*i ----
  int rb = b - 8192;                      // 0..511
  int wave = threadIdx.x >> 6;
  int lane = threadIdx.x & 63;
  int t0 = (rb * 4 + wave) * 2;

  float acc[16];
#pragma unroll
  for (int j = 0; j < 16; ++j) acc[j] = 0.f;

#pragma unroll
  for (int i = 0; i < DDIM / 64; ++i) {
    int d = i * 64 + lane;
    float4 w0 = *(const float4*)(Wr + (size_t)d * E);
    float4 w1 = *(const float4*)(Wr + (size_t)d * E + 4);
#pragma unroll
    for (int t = 0; t < 2; ++t) {
      float xv = x[(size_t)(t0 + t) * DDIM + d];
      xb[(size_t)(t0 + t) * DDIM + d] = (bf16)xv;
      acc[t * 8 + 0] += xv * w0.x; acc[t * 8 + 1] += xv * w0.y;
      acc[t * 8 + 2] += xv * w0.z; acc[t * 8 + 3] += xv * w0.w;
      acc[t * 8 + 4] += xv * w1.x; acc[t * 8 + 5] += xv * w1.y;
      acc[t * 8 + 6] += xv * w1.z; acc[t * 8 + 7] += xv * w1.w;
    }
  }
#pragma unroll
  for (int off = 32; off > 0; off >>= 1) {
#pragma unroll
    for (int j = 0; j < 16; ++j) acc[j] += __shfl_xor(acc[j], off, 64);
  }
  if (lane == 0) {
#pragma unroll
    for (int t = 0; t < 2; ++t) {
      int tt = t0 + t;
      float lg[E];
#pragma unroll
      for (int e = 0; e < E; ++e) lg[e] = acc[t * 8 + e] + br[e];
      int e0 = 0;
#pragma unroll
      for (int e = 1; e < E; ++e) if (lg[e] > lg[e0]) e0 = e;
      int e1 = (e0 == 0) ? 1 : 0;
#pragma unroll
      for (int e = 0; e < E; ++e) if (e != e0 && lg[e] > lg[e1]) e1 = e;
      float ex = expf(lg[e1] - lg[e0]);
      float s = 1.f + ex;
      topk_e[2 * tt]     = e0;
      topk_e[2 * tt + 1] = e1;
      topk_g[2 * tt]     = 1.f / s;
      topk_g[2 * tt + 1] = ex / s;
    }
  }
}

// ======== scan+scatter: ONE single-block launch (replaces init+scan+scatter) ========
// Pass 1: ballot-aggregated LDS histogram of topk_e. Thread 0: prefix sums,
// blockmap, global counts/offsets/nblk. Pass 2: ballot-aggregated LDS-cursor
// scatter -> rowtok/tokrow. Row order within an expert is arbitrary but
// self-consistent (rowtok/tokrow from the same atomic), so output is invariant.
__global__ __launch_bounds__(256) void scan_scatter_kernel(
    const int* __restrict__ topk_e,
    int* __restrict__ counts,    // stride 16 ints per expert
    int* __restrict__ offsets,
    int* __restrict__ blockmap, int* __restrict__ nblk,
    int* __restrict__ rowtok, int* __restrict__ tokrow) {
  __shared__ int hist[E], curs[E];
  int tid = threadIdx.x;
  int lane = tid & 63;
  unsigned long long lt = ((unsigned long long)1 << lane) - 1;
  if (tid < E) hist[tid] = 0;
  __syncthreads();
  for (int i = tid; i < 2 * NTOK; i += 256) {
    int e = topk_e[i];
#pragma unroll
    for (int ee = 0; ee < E; ++ee) {
      unsigned long long m = __ballot(e == ee);
      if (m && lane == __ffsll((long long)m) - 1) atomicAdd(&hist[ee], __popcll(m));
    }
  }
  __syncthreads();
  if (tid == 0) {
    int s = 0, nb = 0;
    for (int e = 0; e < E; ++e) {
      int c = hist[e];
      curs[e] = s;
      counts[e * 16] = c;
      offsets[e] = s;
      int nt = (c + 127) >> 7;
      for (int m = 0; m < nt; ++m) blockmap[nb++] = (e << 16) | m;
      s += c;
    }
    offsets[E] = s;
    nblk[0] = nb;
  }
  __syncthreads();
  for (int i = tid; i < 2 * NTOK; i += 256) {
    int e = topk_e[i];
#pragma unroll
    for (int ee = 0; ee < E; ++ee) {
      unsigned long long m = __ballot(e == ee);
      if (m) {
        int leader = __ffsll((long long)m) - 1;
        int base = 0;
        if (lane == leader) base = atomicAdd(&curs[ee], __popcll(m));
        base = __shfl(base, leader, 64);
        if (e == ee) {
          int row = base + __popcll(m & lt);
          rowtok[row] = i >> 1;
          tokrow[i] = row;
        }
      }
    }
  }
}

// -------- grouped FFN GEMM: round-1 shell verbatim (best measured: 81us, 0 conflicts) --
// BK=64, double-buffered gload_lds, counted vmcnt(8), asm ds_read + both-sides
// XOR swizzle, T1 bijective XCD remap (72 % 8 == 0).
template <bool GATHER, bool RELU>
__global__ __launch_bounds__(256) void ffn_gemm(
    const bf16* __restrict__ A, const bf16* __restrict__ W,
    const float* __restrict__ bias, bf16* __restrict__ Y,
    const int* __restrict__ rowtok, const int* __restrict__ offsets,
    const int* __restrict__ counts,   // stride 16
    const int* __restrict__ blockmap, const int* __restrict__ nblk,
    int Kdim, int Ndim) {
  static_assert(MAXBLK == 72, "XCD remap assumes gridDim.x == 72 == 8*9");
  int xcd = blockIdx.x & 7;
  int idx = blockIdx.y * (MAXBLK / 8) + (blockIdx.x >> 3);
  int mIdx = idx % MAXBLK;
  int nIdx = xcd + 8 * (idx / MAXBLK);
  if (mIdx >= nblk[0]) return;   // ghosts
  int bm = blockmap[mIdx];
  int e = bm >> 16;
  int mBase = (bm & 0xffff) << 7;
  int cnt = counts[e * 16];
  int rowBase = offsets[e] + mBase;
  int nBase = nIdx * 128;
  int validRows = cnt - mBase; if (validRows > 128) validRows = 128;

  __shared__ bf16 Asm[2][128 * 64];
  __shared__ bf16 Bsm[2][128 * 64];

  int tid = threadIdx.x;
  int wave = tid >> 6, lane = tid & 63;
  int lrow = lane >> 3;     // 0..7  row within 8-row chunk
  int lseg = lane & 7;      // 16B segment within 128B row
  int sseg = lseg ^ lrow;   // T2: pre-swizzled SOURCE segment (LDS dest linear)

  const bf16* aptr[4];
  const bf16* bptr[4];
#pragma unroll
  for (int i = 0; i < 4; ++i) {
    int c = wave + i * 4;
    int r = rowBase + c * 8 + lrow;
    if (r > MAXROWS - 1) r = MAXROWS - 1;   // partial tile: harmless dup, masked at store
    size_t rowoff = GATHER ? (size_t)rowtok[r] * Kdim : (size_t)r * Kdim;
    aptr[i] = A + rowoff + sseg * 8;
    bptr[i] = W + ((size_t)e * Ndim + nBase + c * 8 + lrow) * (size_t)Kdim + sseg * 8;
  }

  floatx4 acc[4][4];
#pragma unroll
  for (int m = 0; m < 4; ++m)
#pragma unroll
    for (int n = 0; n < 4; ++n) acc[m][n] = floatx4{0.f, 0.f, 0.f, 0.f};

  int wm = wave & 1, wn = wave >> 1;        // 2x2 wave grid, each wave 64x64
  int mrow = lane & 15;
  int kseg0 = lane >> 4;    // 0..3
  int swz = mrow & 7;       // T2 read-side XOR

  auto issue = [&](int p, int kc) {
#pragma unroll
    for (int i = 0; i < 4; ++i) {
      int c = wave + i * 4;
      gload_lds16(aptr[i] + kc, &Asm[p][c * 512]);
      gload_lds16(bptr[i] + kc, &Bsm[p][c * 512]);
    }
  };

  issue(0, 0);
  int p = 0;
  for (int kc = 0; kc < Kdim; kc += 64) {
    if (kc + 64 < Kdim) {
      issue(p ^ 1, kc + 64);
      asm volatile("s_waitcnt vmcnt(8)" ::: "memory");   // tile t done; next in flight
    } else {
      asm volatile("s_waitcnt vmcnt(0)" ::: "memory");
    }
    asm volatile("s_barrier" ::: "memory");

    bf16x8 af[2][4], bfr[2][4];
#pragma unroll
    for (int ks = 0; ks < 2; ++ks) {
      int kk = (((ks << 2) | kseg0) ^ swz) << 3;   // element offset within 64-wide row
#pragma unroll
      for (int m = 0; m < 4; ++m)
        af[ks][m] = ds_read16(&Asm[p][(wm * 64 + m * 16 + mrow) * 64 + kk]);
#pragma unroll
      for (int n = 0; n < 4; ++n)
        bfr[ks][n] = ds_read16(&Bsm[p][(wn * 64 + n * 16 + mrow) * 64 + kk]);
    }
    asm volatile("s_waitcnt lgkmcnt(0)" ::: "memory");
    __builtin_amdgcn_sched_barrier(0);   // rule #18: MFMAs stay below the lgkm wait

#pragma unroll
    for (int ks = 0; ks < 2; ++ks)
#pragma unroll
      for (int m = 0; m < 4; ++m)
#pragma unroll
        for (int n = 0; n < 4; ++n)
          acc[m][n] = __builtin_amdgcn_mfma_f32_16x16x32_bf16(af[ks][m], bfr[ks][n], acc[m][n], 0, 0, 0);

    asm volatile("s_barrier" ::: "memory");   // all waves' reads of buf p done
    p ^= 1;
  }

  // epilogue: C/D layout col=lane&15, row=(lane>>4)*4+reg  [m89-verified]
  int crow = (lane >> 4) * 4;
  int ccol = lane & 15;
#pragma unroll
  for (int n = 0; n < 4; ++n) {
    int colg = nBase + wn * 64 + n * 16 + ccol;
    float bv = bias[(size_t)e * Ndim + colg];
#pragma unroll
    for (int m = 0; m < 4; ++m) {
#pragma unroll
      for (int r = 0; r < 4; ++r) {
        int rl = wm * 64 + m * 16 + crow + r;
        if (rl < validRows) {
          float v = acc[m][n][r] + bv;
          if (RELU) v = fmaxf(v, 0.f);
          Y[(size_t)(rowBase + rl) * Ndim + colg] = (bf16)v;
        }
      }
    }
  }
}

// ---------------- combine: out[t] = g0*Y2[r0] + g1*Y2[r1]  (fp32 out) ----------------
__global__ void combine_kernel(const bf16* __restrict__ Y2,
                               const int* __restrict__ tokrow,
                               const float* __restrict__ topk_g,
                               float* __restrict__ out) {
  int idx = blockIdx.x * 256 + threadIdx.x;
  int t = idx >> 7;              // DDIM/8 = 128 vectors per token
  int d8 = (idx & 127) * 8;
  int r0 = tokrow[2 * t], r1 = tokrow[2 * t + 1];
  float g0 = topk_g[2 * t], g1 = topk_g[2 * t + 1];
  bf16x8 a = *(const bf16x8*)(Y2 + (size_t)r0 * DDIM + d8);
  bf16x8 b = *(const bf16x8*)(Y2 + (size_t)r1 * DDIM + d8);
  float o[8];
#pragma unroll
  for (int j = 0; j < 8; ++j) o[j] = g0 * (float)a[j] + g1 * (float)b[j];
  float* op = out + (size_t)t * DDIM + d8;
  *(float4*)op = *(float4*)&o[0];
  *(float4*)(op + 4) = *(float4*)&o[4];
}

}  // namespace

extern "C" void kernel_launch(void* const* d_in, const int* in_sizes, int n_in,
                              void* d_out, int out_size, void* d_ws, size_t ws_size,
                              hipStream_t stream) {
  const float* x  = (const float*)d_in[0];   // [B,T,D] fp32
  const float* Wr = (const float*)d_in[1];   // [D,E]   fp32
  const float* br = (const float*)d_in[2];   // [E]     fp32
  const float* W1 = (const float*)d_in[3];   // [E,D,H] fp32
  const float* b1 = (const float*)d_in[4];   // [E,H]   fp32
  const float* W2 = (const float*)d_in[5];   // [E,H,D] fp32
  const float* b2 = (const float*)d_in[6];   // [E,D]   fp32
  float* out = (float*)d_out;                // [B,T,D] fp32

  char* w = (char*)d_ws;
  int*   counts   = (int*)(w);               // 8 experts, stride 16 ints (64B apart)
  int*   offsets  = (int*)(w + 1024);        // 9 ints
  int*   blockmap = (int*)(w + 2048);        // 72 ints
  int*   nblk     = (int*)(w + 2048 + 512);
  int*   topk_e   = (int*)(w + 4096);
  float* topk_g   = (float*)(w + 4096 + 32768);
  int*   rowtok   = (int*)(w + 4096 + 65536);
  int*   tokrow   = (int*)(w + 4096 + 98304);
  char*  big      = w + 4096 + 131072;
  bf16* xb  = (bf16*)(big);                        // [4096][D]  bf16   8.4 MB
  bf16* W1T = (bf16*)(big + 8388608);              // [E][H][D]  bf16  33.5 MB
  bf16* W2T = (bf16*)(big + 8388608 + 33554432);   // [E][D][H]  bf16  33.5 MB
  bf16* Y1  = (bf16*)(big + 8388608 + 67108864);   // [8192][H]  bf16  33.5 MB
  bf16* Y2  = (bf16*)(big + 8388608);              // alias W1T (dead after GEMM1)

  // 5 launches total (was 9): prep(transposes+router) -> scan_scatter -> 2x GEMM -> combine
  prep_kernel<<<8704, 256, 0, stream>>>(x, Wr, br, W1, W2, topk_e, topk_g, xb, W1T, W2T);
  scan_scatter_kernel<<<1, 256, 0, stream>>>(topk_e, counts, offsets, blockmap, nblk,
                                             rowtok, tokrow);
  ffn_gemm<true, true><<<dim3(MAXBLK, HDIM / 128), 256, 0, stream>>>(
      xb, W1T, b1, Y1, rowtok, offsets, counts, blockmap, nblk, DDIM, HDIM);
  ffn_gemm<false, false><<<dim3(MAXBLK, DDIM / 128), 256, 0, stream>>>(
      Y1, W2T, b2, Y2, rowtok, offsets, counts, blockmap, nblk, HDIM, DDIM);
  combine_kernel<<<NTOK * DDIM / 8 / 256, 256, 0, stream>>>(Y2, tokrow, topk_g, out);
}

// Round 5
// 370.422 us; speedup vs baseline: 1.0895x; 1.0895x over previous
//
#include <hip/hip_runtime.h>
#include <hip/hip_bf16.h>
#include <math.h>

namespace {

constexpr int NTOK   = 4096;   // B*T
constexpr int DDIM   = 1024;
constexpr int E      = 8;
constexpr int HDIM   = 2048;
constexpr int MAXROWS = 8192;  // NTOK * K (every token -> exactly 2 rows)
constexpr int MAXBLK  = 72;    // 8 XCD chunks x 9 slots (>= sum_e ceil(cnt_e/128) <= 71)

typedef __bf16 bf16;
typedef __attribute__((ext_vector_type(8))) __bf16 bf16x8;
typedef __attribute__((ext_vector_type(4))) float floatx4;
typedef __attribute__((ext_vector_type(4))) int   i32x4;

// async global->LDS, 16B per lane; LDS dest = WAVE-UNIFORM base, HW adds lane*16
__device__ inline void gload_lds16(const bf16* g, bf16* l) {
  __builtin_amdgcn_global_load_lds(
      (const __attribute__((address_space(1))) void*)g,
      (__attribute__((address_space(3))) void*)l, 16, 0, 0);
}

// inline-asm ds_read_b128: invisible to the waitcnt pass (no conservative vmcnt(0)
// drain of in-flight prefetch). Discipline: explicit lgkmcnt(0) + sched_barrier(0)
// before the consuming MFMAs (rule #18).
__device__ inline bf16x8 ds_read16(const bf16* p) {
  i32x4 r;
  asm volatile("ds_read_b128 %0, %1"
               : "=v"(r)
               : "v"((const __attribute__((address_space(3))) bf16*)p));
  return __builtin_bit_cast(bf16x8, r);
}

__device__ inline unsigned short bfbits(float f) {
  return __builtin_bit_cast(unsigned short, (bf16)f);
}

// -------- transpose+cast tile body: 256 rows x 64 cols; fp32 [R][C] -> bf16 [C][R] ----
// LDS holds the TRANSPOSED tile (tileT[c][r], pad 264 -> row 528B, 16B-aligned), so
// the global write reads ds_read_b128 and emits 512B contiguous bursts per half-wave
// (vs 128B before). Reads pack row-pairs into u32 LDS stores. LDS bank conflicts are
// irrelevant here: block moves 96KB of HBM vs 64KB of LDS -- HBM-bound by ~30x.
__device__ inline void transpose_tile256(const float* __restrict__ src,
                                         bf16* __restrict__ dst,
                                         int R, int C, int c0, int r0,
                                         unsigned short (*tileT)[264]) {
  int tid = threadIdx.x;
  int rp = (tid >> 4) * 2;        // 0,2,...,30
  int tc = (tid & 15) * 4;        // 0..60
#pragma unroll
  for (int i = 0; i < 8; ++i) {
    int r = rp + i * 32;          // even row; pair (r, r+1)
    float4 v0 = *(const float4*)(src + (size_t)(r0 + r)     * C + c0 + tc);
    float4 v1 = *(const float4*)(src + (size_t)(r0 + r + 1) * C + c0 + tc);
    // tileT[c][r] = src[r][c]; pack two rows into one u32 store (r even)
    *(unsigned int*)&tileT[tc + 0][r] = (unsigned int)bfbits(v0.x) | ((unsigned int)bfbits(v1.x) << 16);
    *(unsigned int*)&tileT[tc + 1][r] = (unsigned int)bfbits(v0.y) | ((unsigned int)bfbits(v1.y) << 16);
    *(unsigned int*)&tileT[tc + 2][r] = (unsigned int)bfbits(v0.z) | ((unsigned int)bfbits(v1.z) << 16);
    *(unsigned int*)&tileT[tc + 3][r] = (unsigned int)bfbits(v0.w) | ((unsigned int)bfbits(v1.w) << 16);
  }
  __syncthreads();
  int tc2 = (tid & 31) * 8;       // row offset within column, 0..248
  int tr2 = tid >> 5;             // 0..7
#pragma unroll
  for (int i = 0; i < 8; ++i) {
    int c = tr2 + i * 8;          // 0..63
    *(bf16x8*)(dst + (size_t)(c0 + c) * R + r0 + tc2) =
        *(const bf16x8*)&tileT[c][tc2];
  }
}

// ======== prep: ONE launch = W1 transpose + W2 transpose + router ========
// blocks [0,1024)      : W1 [E][D][H] fp32 -> W1T [E][H][D] bf16  (4 r x 32 c x 8 e)
// blocks [1024,2048)   : W2 [E][H][D] fp32 -> W2T [E][D][H] bf16  (8 r x 16 c x 8 e)
// blocks [2048,2560)   : router (logits, top-2, gates, bf16 cast of x)
__global__ __launch_bounds__(256) void prep_kernel(
    const float* __restrict__ x,  const float* __restrict__ Wr,
    const float* __restrict__ br, const float* __restrict__ W1,
    const float* __restrict__ W2,
    int* __restrict__ topk_e, float* __restrict__ topk_g,
    bf16* __restrict__ xb, bf16* __restrict__ W1T, bf16* __restrict__ W2T) {
  __shared__ unsigned short tileT[64][264];   // 33.8 KB
  int b = blockIdx.x;
  if (b < 1024) {
    int bx = b & 31, by = (b >> 5) & 3, bz = b >> 7;
    const float* src = W1 + (size_t)bz * DDIM * HDIM;
    bf16* dst = W1T + (size_t)bz * DDIM * HDIM;
    transpose_tile256(src, dst, DDIM, HDIM, bx * 64, by * 256, tileT);
    return;
  }
  if (b < 2048) {
    int lb = b - 1024;
    int bx = lb & 15, by = (lb >> 4) & 7, bz = lb >> 7;
    const float* src = W2 + (size_t)bz * DDIM * HDIM;
    bf16* dst = W2T + (size_t)bz * DDIM * HDIM;
    transpose_tile256(src, dst, HDIM, DDIM, bx * 64, by * 256, tileT);
    return;
  }
  // ---- router: wave = 2 tokens; lane l owns channels d = l + 64*i ----
  int rb = b - 2048;                      // 0..511
  int wave = threadIdx.x >> 6;
  int lane = threadIdx.x & 63;
  int t0 = (rb * 4 + wave) * 2;

  float acc[16];
#pragma unroll
  for (int j = 0; j < 16; ++j) acc[j] = 0.f;

#pragma unroll
  for (int i = 0; i < DDIM / 64; ++i) {
    int d = i * 64 + lane;
    float4 w0 = *(const float4*)(Wr + (size_t)d * E);
    float4 w1 = *(const float4*)(Wr + (size_t)d * E + 4);
#pragma unroll
    for (int t = 0; t < 2; ++t) {
      float xv = x[(size_t)(t0 + t) * DDIM + d];
      xb[(size_t)(t0 + t) * DDIM + d] = (bf16)xv;
      acc[t * 8 + 0] += xv * w0.x; acc[t * 8 + 1] += xv * w0.y;
      acc[t * 8 + 2] += xv * w0.z; acc[t * 8 + 3] += xv * w0.w;
      acc[t * 8 + 4] += xv * w1.x; acc[t * 8 + 5] += xv * w1.y;
      acc[t * 8 + 6] += xv * w1.z; acc[t * 8 + 7] += xv * w1.w;
    }
  }
#pragma unroll
  for (int off = 32; off > 0; off >>= 1) {
#pragma unroll
    for (int j = 0; j < 16; ++j) acc[j] += __shfl_xor(acc[j], off, 64);
  }
  if (lane == 0) {
#pragma unroll
    for (int t = 0; t < 2; ++t) {
      int tt = t0 + t;
      float lg[E];
#pragma unroll
      for (int e = 0; e < E; ++e) lg[e] = acc[t * 8 + e] + br[e];
      int e0 = 0;
#pragma unroll
      for (int e = 1; e < E; ++e) if (lg[e] > lg[e0]) e0 = e;
      int e1 = (e0 == 0) ? 1 : 0;
#pragma unroll
      for (int e = 0; e < E; ++e) if (e != e0 && lg[e] > lg[e1]) e1 = e;
      float ex = expf(lg[e1] - lg[e0]);
      float s = 1.f + ex;
      topk_e[2 * tt]     = e0;
      topk_e[2 * tt + 1] = e1;
      topk_g[2 * tt]     = 1.f / s;
      topk_g[2 * tt + 1] = ex / s;
    }
  }
}

// ======== scan+scatter: single block, 1024 threads ========
// Pass 1: ballot-aggregated LDS histogram. Thread 0: prefix sums + BALANCED padded
// blockmap (live tiles split evenly into 8 XCD chunks of 9 slots, pads = -1, order
// preserved so chunks stay expert-contiguous). Pass 2: ballot LDS-cursor scatter.
__global__ __launch_bounds__(1024) void scan_scatter_kernel(
    const int* __restrict__ topk_e,
    int* __restrict__ counts,    // stride 16 ints per expert
    int* __restrict__ offsets,
    int* __restrict__ blockmap,  // [MAXBLK] packed e<<16|mtile, -1 = ghost
    int* __restrict__ rowtok, int* __restrict__ tokrow) {
  __shared__ int hist[E], curs[E];
  int tid = threadIdx.x;
  int lane = tid & 63;
  unsigned long long lt = ((unsigned long long)1 << lane) - 1;
  if (tid < E) hist[tid] = 0;
  __syncthreads();
  for (int i = tid; i < 2 * NTOK; i += 1024) {
    int e = topk_e[i];
#pragma unroll
    for (int ee = 0; ee < E; ++ee) {
      unsigned long long m = __ballot(e == ee);
      if (m && lane == __ffsll((long long)m) - 1) atomicAdd(&hist[ee], __popcll(m));
    }
  }
  __syncthreads();
  if (tid == 0) {
    int live[MAXBLK];
    int s = 0, nb = 0;
    for (int e = 0; e < E; ++e) {
      int c = hist[e];
      curs[e] = s;
      counts[e * 16] = c;
      offsets[e] = s;
      int nt = (c + 127) >> 7;
      for (int m = 0; m < nt; ++m) live[nb++] = (e << 16) | m;
      s += c;
    }
    offsets[E] = s;
    // balanced padded blockmap: chunk x (slots [9x,9x+9)) gets live [nb*x/8, nb*(x+1)/8)
    for (int xc = 0; xc < 8; ++xc) {
      int lo = (nb * xc) >> 3, hi = (nb * (xc + 1)) >> 3;
      for (int j = 0; j < 9; ++j)
        blockmap[9 * xc + j] = (lo + j < hi) ? live[lo + j] : -1;
    }
  }
  __syncthreads();
  for (int i = tid; i < 2 * NTOK; i += 1024) {
    int e = topk_e[i];
#pragma unroll
    for (int ee = 0; ee < E; ++ee) {
      unsigned long long m = __ballot(e == ee);
      if (m) {
        int leader = __ffsll((long long)m) - 1;
        int base = 0;
        if (lane == leader) base = atomicAdd(&curs[ee], __popcll(m));
        base = __shfl(base, leader, 64);
        if (e == ee) {
          int row = base + __popcll(m & lt);
          rowtok[row] = i >> 1;
          tokrow[i] = row;
        }
      }
    }
  }
}

// -------- grouped FFN GEMM: round-1 inner loop (81us, 0 conflicts) + m-chunked XCD map --
// NEW map: XCD x owns blockmap chunk [9x, 9x+9) (contiguous m-tiles, expert-sorted)
// and sweeps n inner -> A-chunk (<=2.25MB) stays L2-resident across all n-strips;
// each A-tile is fetched from HBM once globally. W panels stream per expert.
template <bool GATHER, bool RELU>
__global__ __launch_bounds__(256) void ffn_gemm(
    const bf16* __restrict__ A, const bf16* __restrict__ W,
    const float* __restrict__ bias, bf16* __restrict__ Y,
    const int* __restrict__ rowtok, const int* __restrict__ offsets,
    const int* __restrict__ counts,   // stride 16
    const int* __restrict__ blockmap,
    int Kdim, int Ndim) {
  static_assert(MAXBLK == 72, "XCD chunking assumes gridDim.x == 72 == 8*9");
  int xcd = blockIdx.x & 7;           // 72 % 8 == 0: bx&7 = XCD for every by row
  int mq  = blockIdx.x >> 3;          // 0..8 slot within chunk
  int bm = blockmap[xcd * 9 + mq];
  if (bm < 0) return;                 // balanced ghosts
  int e = bm >> 16;
  int mBase = (bm & 0xffff) << 7;
  int cnt = counts[e * 16];
  int rowBase = offsets[e] + mBase;
  int nBase = blockIdx.y * 128;
  int validRows = cnt - mBase; if (validRows > 128) validRows = 128;

  __shared__ bf16 Asm[2][128 * 64];
  __shared__ bf16 Bsm[2][128 * 64];

  int tid = threadIdx.x;
  int wave = tid >> 6, lane = tid & 63;
  int lrow = lane >> 3;     // 0..7  row within 8-row chunk
  int lseg = lane & 7;      // 16B segment within 128B row
  int sseg = lseg ^ lrow;   // T2: pre-swizzled SOURCE segment (LDS dest linear)

  const bf16* aptr[4];
  const bf16* bptr[4];
#pragma unroll
  for (int i = 0; i < 4; ++i) {
    int c = wave + i * 4;
    int r = rowBase + c * 8 + lrow;
    if (r > MAXROWS - 1) r = MAXROWS - 1;   // partial tile: harmless dup, masked at store
    size_t rowoff = GATHER ? (size_t)rowtok[r] * Kdim : (size_t)r * Kdim;
    aptr[i] = A + rowoff + sseg * 8;
    bptr[i] = W + ((size_t)e * Ndim + nBase + c * 8 + lrow) * (size_t)Kdim + sseg * 8;
  }

  floatx4 acc[4][4];
#pragma unroll
  for (int m = 0; m < 4; ++m)
#pragma unroll
    for (int n = 0; n < 4; ++n) acc[m][n] = floatx4{0.f, 0.f, 0.f, 0.f};

  int wm = wave & 1, wn = wave >> 1;        // 2x2 wave grid, each wave 64x64
  int mrow = lane & 15;
  int kseg0 = lane >> 4;    // 0..3
  int swz = mrow & 7;       // T2 read-side XOR

  auto issue = [&](int p, int kc) {
#pragma unroll
    for (int i = 0; i < 4; ++i) {
      int c = wave + i * 4;
      gload_lds16(aptr[i] + kc, &Asm[p][c * 512]);
      gload_lds16(bptr[i] + kc, &Bsm[p][c * 512]);
    }
  };

  issue(0, 0);
  int p = 0;
  for (int kc = 0; kc < Kdim; kc += 64) {
    if (kc + 64 < Kdim) {
      issue(p ^ 1, kc + 64);
      asm volatile("s_waitcnt vmcnt(8)" ::: "memory");   // tile t done; next in flight
    } else {
      asm volatile("s_waitcnt vmcnt(0)" ::: "memory");
    }
    asm volatile("s_barrier" ::: "memory");

    bf16x8 af[2][4], bfr[2][4];
#pragma unroll
    for (int ks = 0; ks < 2; ++ks) {
      int kk = (((ks << 2) | kseg0) ^ swz) << 3;   // element offset within 64-wide row
#pragma unroll
      for (int m = 0; m < 4; ++m)
        af[ks][m] = ds_read16(&Asm[p][(wm * 64 + m * 16 + mrow) * 64 + kk]);
#pragma unroll
      for (int n = 0; n < 4; ++n)
        bfr[ks][n] = ds_read16(&Bsm[p][(wn * 64 + n * 16 + mrow) * 64 + kk]);
    }
    asm volatile("s_waitcnt lgkmcnt(0)" ::: "memory");
    __builtin_amdgcn_sched_barrier(0);   // rule #18: MFMAs stay below the lgkm wait

#pragma unroll
    for (int ks = 0; ks < 2; ++ks)
#pragma unroll
      for (int m = 0; m < 4; ++m)
#pragma unroll
        for (int n = 0; n < 4; ++n)
          acc[m][n] = __builtin_amdgcn_mfma_f32_16x16x32_bf16(af[ks][m], bfr[ks][n], acc[m][n], 0, 0, 0);

    asm volatile("s_barrier" ::: "memory");   // all waves' reads of buf p done
    p ^= 1;
  }

  // epilogue: C/D layout col=lane&15, row=(lane>>4)*4+reg  [m89-verified]
  int crow = (lane >> 4) * 4;
  int ccol = lane & 15;
#pragma unroll
  for (int n = 0; n < 4; ++n) {
    int colg = nBase + wn * 64 + n * 16 + ccol;
    float bv = bias[(size_t)e * Ndim + colg];
#pragma unroll
    for (int m = 0; m < 4; ++m) {
#pragma unroll
      for (int r = 0; r < 4; ++r) {
        int rl = wm * 64 + m * 16 + crow + r;
        if (rl < validRows) {
          float v = acc[m][n][r] + bv;
          if (RELU) v = fmaxf(v, 0.f);
          Y[(size_t)(rowBase + rl) * Ndim + colg] = (bf16)v;
        }
      }
    }
  }
}

// ---------------- combine: out[t] = g0*Y2[r0] + g1*Y2[r1]  (fp32 out) ----------------
__global__ void combine_kernel(const bf16* __restrict__ Y2,
                               const int* __restrict__ tokrow,
                               const float* __restrict__ topk_g,
                               float* __restrict__ out) {
  int idx = blockIdx.x * 256 + threadIdx.x;
  int t = idx >> 7;              // DDIM/8 = 128 vectors per token
  int d8 = (idx & 127) * 8;
  int r0 = tokrow[2 * t], r1 = tokrow[2 * t + 1];
  float g0 = topk_g[2 * t], g1 = topk_g[2 * t + 1];
  bf16x8 a = *(const bf16x8*)(Y2 + (size_t)r0 * DDIM + d8);
  bf16x8 b = *(const bf16x8*)(Y2 + (size_t)r1 * DDIM + d8);
  float o[8];
#pragma unroll
  for (int j = 0; j < 8; ++j) o[j] = g0 * (float)a[j] + g1 * (float)b[j];
  float* op = out + (size_t)t * DDIM + d8;
  *(float4*)op = *(float4*)&o[0];
  *(float4*)(op + 4) = *(float4*)&o[4];
}

}  // namespace

extern "C" void kernel_launch(void* const* d_in, const int* in_sizes, int n_in,
                              void* d_out, int out_size, void* d_ws, size_t ws_size,
                              hipStream_t stream) {
  const float* x  = (const float*)d_in[0];   // [B,T,D] fp32
  const float* Wr = (const float*)d_in[1];   // [D,E]   fp32
  const float* br = (const float*)d_in[2];   // [E]     fp32
  const float* W1 = (const float*)d_in[3];   // [E,D,H] fp32
  const float* b1 = (const float*)d_in[4];   // [E,H]   fp32
  const float* W2 = (const float*)d_in[5];   // [E,H,D] fp32
  const float* b2 = (const float*)d_in[6];   // [E,D]   fp32
  float* out = (float*)d_out;                // [B,T,D] fp32

  char* w = (char*)d_ws;
  int*   counts   = (int*)(w);               // 8 experts, stride 16 ints (64B apart)
  int*   offsets  = (int*)(w + 1024);        // 9 ints
  int*   blockmap = (int*)(w + 2048);        // 72 ints
  int*   topk_e   = (int*)(w + 4096);
  float* topk_g   = (float*)(w + 4096 + 32768);
  int*   rowtok   = (int*)(w + 4096 + 65536);
  int*   tokrow   = (int*)(w + 4096 + 98304);
  char*  big      = w + 4096 + 131072;
  bf16* xb  = (bf16*)(big);                        // [4096][D]  bf16   8.4 MB
  bf16* W1T = (bf16*)(big + 8388608);              // [E][H][D]  bf16  33.5 MB
  bf16* W2T = (bf16*)(big + 8388608 + 33554432);   // [E][D][H]  bf16  33.5 MB
  bf16* Y1  = (bf16*)(big + 8388608 + 67108864);   // [8192][H]  bf16  33.5 MB
  bf16* Y2  = (bf16*)(big + 8388608);              // alias W1T (dead after GEMM1)

  // 5 launches: prep(transposes+router) -> scan_scatter -> 2x GEMM -> combine
  prep_kernel<<<2560, 256, 0, stream>>>(x, Wr, br, W1, W2, topk_e, topk_g, xb, W1T, W2T);
  scan_scatter_kernel<<<1, 1024, 0, stream>>>(topk_e, counts, offsets, blockmap,
                                              rowtok, tokrow);
  ffn_gemm<true, true><<<dim3(MAXBLK, HDIM / 128), 256, 0, stream>>>(
      xb, W1T, b1, Y1, rowtok, offsets, counts, blockmap, DDIM, HDIM);
  ffn_gemm<false, false><<<dim3(MAXBLK, DDIM / 128), 256, 0, stream>>>(
      Y1, W2T, b2, Y2, rowtok, offsets, counts, blockmap, HDIM, DDIM);
  combine_kernel<<<NTOK * DDIM / 8 / 256, 256, 0, stream>>>(Y2, tokrow, topk_g, out);
}

// Round 6
// 349.267 us; speedup vs baseline: 1.1554x; 1.0606x over previous
//
#include <hip/hip_runtime.h>
#include <hip/hip_bf16.h>
#include <math.h>

namespace {

constexpr int NTOK   = 4096;   // B*T
constexpr int DDIM   = 1024;
constexpr int E      = 8;
constexpr int HDIM   = 2048;
constexpr int MAXROWS = 8192;  // NTOK * K (every token -> exactly 2 rows)
constexpr int MAXBLK  = 56;    // 8 XCD chunks x 7 slots (>= sum_e ceil(cnt_e/192) <= 50)

typedef __bf16 bf16;
typedef __attribute__((ext_vector_type(8))) __bf16 bf16x8;
typedef __attribute__((ext_vector_type(4))) float floatx4;
typedef __attribute__((ext_vector_type(4))) int   i32x4;

// async global->LDS, 16B per lane; LDS dest = WAVE-UNIFORM base, HW adds lane*16
__device__ inline void gload_lds16(const bf16* g, bf16* l) {
  __builtin_amdgcn_global_load_lds(
      (const __attribute__((address_space(1))) void*)g,
      (__attribute__((address_space(3))) void*)l, 16, 0, 0);
}

// inline-asm ds_read_b128: invisible to the waitcnt pass (no conservative vmcnt(0)
// drain of in-flight prefetch). Discipline: explicit lgkmcnt(0) + sched_barrier(0)
// before the consuming MFMAs (rule #18).
__device__ inline bf16x8 ds_read16(const bf16* p) {
  i32x4 r;
  asm volatile("ds_read_b128 %0, %1"
               : "=v"(r)
               : "v"((const __attribute__((address_space(3))) bf16*)p));
  return __builtin_bit_cast(bf16x8, r);
}

__device__ inline unsigned short bfbits(float f) {
  return __builtin_bit_cast(unsigned short, (bf16)f);
}

// -------- transpose+cast tile body: 256 rows x 64 cols; fp32 [R][C] -> bf16 [C][R] ----
__device__ inline void transpose_tile256(const float* __restrict__ src,
                                         bf16* __restrict__ dst,
                                         int R, int C, int c0, int r0,
                                         unsigned short (*tileT)[264]) {
  int tid = threadIdx.x;
  int rp = (tid >> 4) * 2;        // 0,2,...,30
  int tc = (tid & 15) * 4;        // 0..60
#pragma unroll
  for (int i = 0; i < 8; ++i) {
    int r = rp + i * 32;          // even row; pair (r, r+1)
    float4 v0 = *(const float4*)(src + (size_t)(r0 + r)     * C + c0 + tc);
    float4 v1 = *(const float4*)(src + (size_t)(r0 + r + 1) * C + c0 + tc);
    *(unsigned int*)&tileT[tc + 0][r] = (unsigned int)bfbits(v0.x) | ((unsigned int)bfbits(v1.x) << 16);
    *(unsigned int*)&tileT[tc + 1][r] = (unsigned int)bfbits(v0.y) | ((unsigned int)bfbits(v1.y) << 16);
    *(unsigned int*)&tileT[tc + 2][r] = (unsigned int)bfbits(v0.z) | ((unsigned int)bfbits(v1.z) << 16);
    *(unsigned int*)&tileT[tc + 3][r] = (unsigned int)bfbits(v0.w) | ((unsigned int)bfbits(v1.w) << 16);
  }
  __syncthreads();
  int tc2 = (tid & 31) * 8;       // row offset within column, 0..248
  int tr2 = tid >> 5;             // 0..7
#pragma unroll
  for (int i = 0; i < 8; ++i) {
    int c = tr2 + i * 8;          // 0..63
    *(bf16x8*)(dst + (size_t)(c0 + c) * R + r0 + tc2) =
        *(const bf16x8*)&tileT[c][tc2];
  }
}

// ======== prep: ONE launch = W1 transpose + W2 transpose + router ========
__global__ __launch_bounds__(256) void prep_kernel(
    const float* __restrict__ x,  const float* __restrict__ Wr,
    const float* __restrict__ br, const float* __restrict__ W1,
    const float* __restrict__ W2,
    int* __restrict__ topk_e, float* __restrict__ topk_g,
    bf16* __restrict__ xb, bf16* __restrict__ W1T, bf16* __restrict__ W2T) {
  __shared__ unsigned short tileT[64][264];   // 33.8 KB
  int b = blockIdx.x;
  if (b < 1024) {
    int bx = b & 31, by = (b >> 5) & 3, bz = b >> 7;
    const float* src = W1 + (size_t)bz * DDIM * HDIM;
    bf16* dst = W1T + (size_t)bz * DDIM * HDIM;
    transpose_tile256(src, dst, DDIM, HDIM, bx * 64, by * 256, tileT);
    return;
  }
  if (b < 2048) {
    int lb = b - 1024;
    int bx = lb & 15, by = (lb >> 4) & 7, bz = lb >> 7;
    const float* src = W2 + (size_t)bz * DDIM * HDIM;
    bf16* dst = W2T + (size_t)bz * DDIM * HDIM;
    transpose_tile256(src, dst, HDIM, DDIM, bx * 64, by * 256, tileT);
    return;
  }
  // ---- router: wave = 2 tokens; lane l owns channels d = l + 64*i ----
  int rb = b - 2048;                      // 0..511
  int wave = threadIdx.x >> 6;
  int lane = threadIdx.x & 63;
  int t0 = (rb * 4 + wave) * 2;

  float acc[16];
#pragma unroll
  for (int j = 0; j < 16; ++j) acc[j] = 0.f;

#pragma unroll
  for (int i = 0; i < DDIM / 64; ++i) {
    int d = i * 64 + lane;
    float4 w0 = *(const float4*)(Wr + (size_t)d * E);
    float4 w1 = *(const float4*)(Wr + (size_t)d * E + 4);
#pragma unroll
    for (int t = 0; t < 2; ++t) {
      float xv = x[(size_t)(t0 + t) * DDIM + d];
      xb[(size_t)(t0 + t) * DDIM + d] = (bf16)xv;
      acc[t * 8 + 0] += xv * w0.x; acc[t * 8 + 1] += xv * w0.y;
      acc[t * 8 + 2] += xv * w0.z; acc[t * 8 + 3] += xv * w0.w;
      acc[t * 8 + 4] += xv * w1.x; acc[t * 8 + 5] += xv * w1.y;
      acc[t * 8 + 6] += xv * w1.z; acc[t * 8 + 7] += xv * w1.w;
    }
  }
#pragma unroll
  for (int off = 32; off > 0; off >>= 1) {
#pragma unroll
    for (int j = 0; j < 16; ++j) acc[j] += __shfl_xor(acc[j], off, 64);
  }
  if (lane == 0) {
#pragma unroll
    for (int t = 0; t < 2; ++t) {
      int tt = t0 + t;
      float lg[E];
#pragma unroll
      for (int e = 0; e < E; ++e) lg[e] = acc[t * 8 + e] + br[e];
      int e0 = 0;
#pragma unroll
      for (int e = 1; e < E; ++e) if (lg[e] > lg[e0]) e0 = e;
      int e1 = (e0 == 0) ? 1 : 0;
#pragma unroll
      for (int e = 0; e < E; ++e) if (e != e0 && lg[e] > lg[e1]) e1 = e;
      float ex = expf(lg[e1] - lg[e0]);
      float s = 1.f + ex;
      topk_e[2 * tt]     = e0;
      topk_e[2 * tt + 1] = e1;
      topk_g[2 * tt]     = 1.f / s;
      topk_g[2 * tt + 1] = ex / s;
    }
  }
}

// ======== scan+scatter: single block, 1024 threads; 192-row m-tiles ========
__global__ __launch_bounds__(1024) void scan_scatter_kernel(
    const int* __restrict__ topk_e,
    int* __restrict__ counts,    // stride 16 ints per expert
    int* __restrict__ offsets,
    int* __restrict__ blockmap,  // [MAXBLK] packed e<<16|mtile, -1 = ghost
    int* __restrict__ rowtok, int* __restrict__ tokrow) {
  __shared__ int hist[E], curs[E];
  int tid = threadIdx.x;
  int lane = tid & 63;
  unsigned long long lt = ((unsigned long long)1 << lane) - 1;
  if (tid < E) hist[tid] = 0;
  __syncthreads();
  for (int i = tid; i < 2 * NTOK; i += 1024) {
    int e = topk_e[i];
#pragma unroll
    for (int ee = 0; ee < E; ++ee) {
      unsigned long long m = __ballot(e == ee);
      if (m && lane == __ffsll((long long)m) - 1) atomicAdd(&hist[ee], __popcll(m));
    }
  }
  __syncthreads();
  if (tid == 0) {
    int live[MAXBLK];
    int s = 0, nb = 0;
    for (int e = 0; e < E; ++e) {
      int c = hist[e];
      curs[e] = s;
      counts[e * 16] = c;
      offsets[e] = s;
      int nt = (c + 191) / 192;
      for (int m = 0; m < nt; ++m) live[nb++] = (e << 16) | m;
      s += c;
    }
    offsets[E] = s;
    // balanced padded blockmap: chunk x (slots [7x,7x+7)) gets live [nb*x/8, nb*(x+1)/8)
    for (int xc = 0; xc < 8; ++xc) {
      int lo = (nb * xc) >> 3, hi = (nb * (xc + 1)) >> 3;
      for (int j = 0; j < 7; ++j)
        blockmap[7 * xc + j] = (lo + j < hi) ? live[lo + j] : -1;
    }
  }
  __syncthreads();
  for (int i = tid; i < 2 * NTOK; i += 1024) {
    int e = topk_e[i];
#pragma unroll
    for (int ee = 0; ee < E; ++ee) {
      unsigned long long m = __ballot(e == ee);
      if (m) {
        int leader = __ffsll((long long)m) - 1;
        int base = 0;
        if (lane == leader) base = atomicAdd(&curs[ee], __popcll(m));
        base = __shfl(base, leader, 64);
        if (e == ee) {
          int row = base + __popcll(m & lt);
          rowtok[row] = i >> 1;
          tokrow[i] = row;
        }
      }
    }
  }
}

// ======== grouped FFN GEMM: 192x128 tile, BK=64, double-buffer, counted vmcnt(10) ======
// Raised arithmetic intensity (79 FLOP/B vs 65): per-CU-step MFMA 1862 cyc > VMEM
// 1430 cyc -> MFMA-dominant. Same proven staging/swizzle/asm-ds_read shell.
// XCD x owns blockmap chunk [7x,7x+7) (contiguous m-tiles) and sweeps n inner.
template <bool GATHER, bool RELU>
__global__ __launch_bounds__(256, 2) void ffn_gemm(
    const bf16* __restrict__ A, const bf16* __restrict__ W,
    const float* __restrict__ bias, bf16* __restrict__ Y,
    const int* __restrict__ rowtok, const int* __restrict__ offsets,
    const int* __restrict__ counts,   // stride 16
    const int* __restrict__ blockmap,
    int Kdim, int Ndim) {
  static_assert(MAXBLK == 56, "XCD chunking assumes gridDim.x == 56 == 8*7");
  int xcd = blockIdx.x & 7;           // 56 % 8 == 0
  int mq  = blockIdx.x >> 3;          // 0..6 slot within chunk
  int bm = blockmap[xcd * 7 + mq];
  if (bm < 0) return;                 // balanced ghosts
  int e = bm >> 16;
  int mBase = (bm & 0xffff) * 192;
  int cnt = counts[e * 16];
  int rowBase = offsets[e] + mBase;
  int nBase = blockIdx.y * 128;
  int validRows = cnt - mBase; if (validRows > 192) validRows = 192;

  __shared__ bf16 Asm[2][192 * 64];   // 24 KB per buf
  __shared__ bf16 Bsm[2][128 * 64];   // 16 KB per buf  (total 80 KB -> 2 blocks/CU)

  int tid = threadIdx.x;
  int wave = tid >> 6, lane = tid & 63;
  int lrow = lane >> 3;     // 0..7  row within 8-row chunk
  int lseg = lane & 7;      // 16B segment within 128B row
  int sseg = lseg ^ lrow;   // T2: pre-swizzled SOURCE segment (LDS dest linear)

  const bf16* aptr[6];
  const bf16* bptr[4];
#pragma unroll
  for (int i = 0; i < 6; ++i) {
    int c = wave + i * 4;             // 0..23 A row-chunks
    int r = rowBase + c * 8 + lrow;
    if (r > MAXROWS - 1) r = MAXROWS - 1;   // partial tile: harmless dup, masked at store
    size_t rowoff = GATHER ? (size_t)rowtok[r] * Kdim : (size_t)r * Kdim;
    aptr[i] = A + rowoff + sseg * 8;
  }
#pragma unroll
  for (int i = 0; i < 4; ++i) {
    int c = wave + i * 4;             // 0..15 B row-chunks
    bptr[i] = W + ((size_t)e * Ndim + nBase + c * 8 + lrow) * (size_t)Kdim + sseg * 8;
  }

  floatx4 acc[6][4];
#pragma unroll
  for (int m = 0; m < 6; ++m)
#pragma unroll
    for (int n = 0; n < 4; ++n) acc[m][n] = floatx4{0.f, 0.f, 0.f, 0.f};

  int wm = wave & 1, wn = wave >> 1;  // wave grid: 2m x 2n; per wave 96 x 64 output
  int mrow = lane & 15;
  int kseg0 = lane >> 4;    // 0..3
  int swz = mrow & 7;       // T2 read-side XOR

  auto issue = [&](int p, int kc) {   // 10 loads per wave (6 A + 4 B)
#pragma unroll
    for (int i = 0; i < 6; ++i) {
      int c = wave + i * 4;
      gload_lds16(aptr[i] + kc, &Asm[p][c * 512]);
    }
#pragma unroll
    for (int i = 0; i < 4; ++i) {
      int c = wave + i * 4;
      gload_lds16(bptr[i] + kc, &Bsm[p][c * 512]);
    }
  };

  issue(0, 0);
  int p = 0;
  for (int kc = 0; kc < Kdim; kc += 64) {
    if (kc + 64 < Kdim) {
      issue(p ^ 1, kc + 64);
      asm volatile("s_waitcnt vmcnt(10)" ::: "memory");  // tile t done; next in flight
    } else {
      asm volatile("s_waitcnt vmcnt(0)" ::: "memory");
    }
    asm volatile("s_barrier" ::: "memory");

#pragma unroll
    for (int ks = 0; ks < 2; ++ks) {
      int kk = (((ks << 2) | kseg0) ^ swz) << 3;   // element offset within 64-wide row
      bf16x8 af[6], bfr[4];
#pragma unroll
      for (int m = 0; m < 6; ++m)
        af[m] = ds_read16(&Asm[p][(wm * 96 + m * 16 + mrow) * 64 + kk]);
#pragma unroll
      for (int n = 0; n < 4; ++n)
        bfr[n] = ds_read16(&Bsm[p][(wn * 64 + n * 16 + mrow) * 64 + kk]);
      asm volatile("s_waitcnt lgkmcnt(0)" ::: "memory");
      __builtin_amdgcn_sched_barrier(0);   // rule #18: MFMAs stay below the lgkm wait
      __builtin_amdgcn_s_setprio(1);
#pragma unroll
      for (int m = 0; m < 6; ++m)
#pragma unroll
        for (int n = 0; n < 4; ++n)
          acc[m][n] = __builtin_amdgcn_mfma_f32_16x16x32_bf16(af[m], bfr[n], acc[m][n], 0, 0, 0);
      __builtin_amdgcn_s_setprio(0);
    }

    asm volatile("s_barrier" ::: "memory");   // all waves' reads of buf p done
    p ^= 1;
  }

  // epilogue: C/D layout col=lane&15, row=(lane>>4)*4+reg  [m89-verified]
  int crow = (lane >> 4) * 4;
  int ccol = lane & 15;
#pragma unroll
  for (int n = 0; n < 4; ++n) {
    int colg = nBase + wn * 64 + n * 16 + ccol;
    float bv = bias[(size_t)e * Ndim + colg];
#pragma unroll
    for (int m = 0; m < 6; ++m) {
#pragma unroll
      for (int r = 0; r < 4; ++r) {
        int rl = wm * 96 + m * 16 + crow + r;
        if (rl < validRows) {
          float v = acc[m][n][r] + bv;
          if (RELU) v = fmaxf(v, 0.f);
          Y[(size_t)(rowBase + rl) * Ndim + colg] = (bf16)v;
        }
      }
    }
  }
}

// ---------------- combine: out[t] = g0*Y2[r0] + g1*Y2[r1]  (fp32 out) ----------------
__global__ void combine_kernel(const bf16* __restrict__ Y2,
                               const int* __restrict__ tokrow,
                               const float* __restrict__ topk_g,
                               float* __restrict__ out) {
  int idx = blockIdx.x * 256 + threadIdx.x;
  int t = idx >> 7;              // DDIM/8 = 128 vectors per token
  int d8 = (idx & 127) * 8;
  int r0 = tokrow[2 * t], r1 = tokrow[2 * t + 1];
  float g0 = topk_g[2 * t], g1 = topk_g[2 * t + 1];
  bf16x8 a = *(const bf16x8*)(Y2 + (size_t)r0 * DDIM + d8);
  bf16x8 b = *(const bf16x8*)(Y2 + (size_t)r1 * DDIM + d8);
  float o[8];
#pragma unroll
  for (int j = 0; j < 8; ++j) o[j] = g0 * (float)a[j] + g1 * (float)b[j];
  float* op = out + (size_t)t * DDIM + d8;
  *(float4*)op = *(float4*)&o[0];
  *(float4*)(op + 4) = *(float4*)&o[4];
}

}  // namespace

extern "C" void kernel_launch(void* const* d_in, const int* in_sizes, int n_in,
                              void* d_out, int out_size, void* d_ws, size_t ws_size,
                              hipStream_t stream) {
  const float* x  = (const float*)d_in[0];   // [B,T,D] fp32
  const float* Wr = (const float*)d_in[1];   // [D,E]   fp32
  const float* br = (const float*)d_in[2];   // [E]     fp32
  const float* W1 = (const float*)d_in[3];   // [E,D,H] fp32
  const float* b1 = (const float*)d_in[4];   // [E,H]   fp32
  const float* W2 = (const float*)d_in[5];   // [E,H,D] fp32
  const float* b2 = (const float*)d_in[6];   // [E,D]   fp32
  float* out = (float*)d_out;                // [B,T,D] fp32

  char* w = (char*)d_ws;
  int*   counts   = (int*)(w);               // 8 experts, stride 16 ints (64B apart)
  int*   offsets  = (int*)(w + 1024);        // 9 ints
  int*   blockmap = (int*)(w + 2048);        // 56 ints
  int*   topk_e   = (int*)(w + 4096);
  float* topk_g   = (float*)(w + 4096 + 32768);
  int*   rowtok   = (int*)(w + 4096 + 65536);
  int*   tokrow   = (int*)(w + 4096 + 98304);
  char*  big      = w + 4096 + 131072;
  bf16* xb  = (bf16*)(big);                        // [4096][D]  bf16   8.4 MB
  bf16* W1T = (bf16*)(big + 8388608);              // [E][H][D]  bf16  33.5 MB
  bf16* W2T = (bf16*)(big + 8388608 + 33554432);   // [E][D][H]  bf16  33.5 MB
  bf16* Y1  = (bf16*)(big + 8388608 + 67108864);   // [8192][H]  bf16  33.5 MB
  bf16* Y2  = (bf16*)(big + 8388608);              // alias W1T (dead after GEMM1)

  // 5 launches: prep(transposes+router) -> scan_scatter -> 2x GEMM -> combine
  prep_kernel<<<2560, 256, 0, stream>>>(x, Wr, br, W1, W2, topk_e, topk_g, xb, W1T, W2T);
  scan_scatter_kernel<<<1, 1024, 0, stream>>>(topk_e, counts, offsets, blockmap,
                                              rowtok, tokrow);
  ffn_gemm<true, true><<<dim3(MAXBLK, HDIM / 128), 256, 0, stream>>>(
      xb, W1T, b1, Y1, rowtok, offsets, counts, blockmap, DDIM, HDIM);
  ffn_gemm<false, false><<<dim3(MAXBLK, DDIM / 128), 256, 0, stream>>>(
      Y1, W2T, b2, Y2, rowtok, offsets, counts, blockmap, HDIM, DDIM);
  combine_kernel<<<NTOK * DDIM / 8 / 256, 256, 0, stream>>>(Y2, tokrow, topk_g, out);
}

// Round 7
// 329.579 us; speedup vs baseline: 1.2245x; 1.0597x over previous
//
#include <hip/hip_runtime.h>
#include <hip/hip_bf16.h>
#include <math.h>

namespace {

constexpr int NTOK   = 4096;   // B*T
constexpr int DDIM   = 1024;
constexpr int E      = 8;
constexpr int HDIM   = 2048;
constexpr int MAXROWS = 8192;  // NTOK * K (every token -> exactly 2 rows)
constexpr int MAXBLK  = 56;    // 8 XCD chunks x 7 slots (>= sum_e ceil(cnt_e/192) <= 50)

typedef __bf16 bf16;
typedef __attribute__((ext_vector_type(8))) __bf16 bf16x8;
typedef __attribute__((ext_vector_type(4))) float floatx4;
typedef __attribute__((ext_vector_type(4))) int   i32x4;

// async global->LDS, 16B per lane; LDS dest = WAVE-UNIFORM base, HW adds lane*16
__device__ inline void gload_lds16(const bf16* g, bf16* l) {
  __builtin_amdgcn_global_load_lds(
      (const __attribute__((address_space(1))) void*)g,
      (__attribute__((address_space(3))) void*)l, 16, 0, 0);
}

// inline-asm ds_read_b128: invisible to the waitcnt pass (no conservative vmcnt(0)
// drain of in-flight prefetch). Discipline: explicit lgkmcnt(0) + sched_barrier(0)
// before the consuming MFMAs (rule #18).
__device__ inline bf16x8 ds_read16(const bf16* p) {
  i32x4 r;
  asm volatile("ds_read_b128 %0, %1"
               : "=v"(r)
               : "v"((const __attribute__((address_space(3))) bf16*)p));
  return __builtin_bit_cast(bf16x8, r);
}

__device__ inline unsigned short bfbits(float f) {
  return __builtin_bit_cast(unsigned short, (bf16)f);
}

// -------- transpose+cast tile: 128 rows x 64 cols; fp32 [R][C] -> bf16 [C][R] --------
// LDS tileT[c][r] with XOR granule swizzle r_phys = r ^ (((c>>2)&7)<<3):
//   writes (u32 row-pair pack): banks = 16(j&1)+4q+(rp/2 ^ 4(j&7)) -> 8 distinct x2
//   lanes = 2-way (free, m136); without swizzle this was 8-way (3.7M conflicts).
//   reads (b128): XOR is uniform per instruction -> pattern unchanged.
// Loads staged in static-indexed float4 arrays so all 8 stay in flight (rule #20).
__device__ inline void transpose_tile128(const float* __restrict__ src,
                                         bf16* __restrict__ dst,
                                         int R, int C, int c0, int r0,
                                         unsigned short (*tileT)[136]) {
  int tid = threadIdx.x;
  int rp = (tid >> 4) * 2;        // 0,2,...,30
  int tc = (tid & 15) * 4;        // 0..60
  float4 v0[4], v1[4];
#pragma unroll
  for (int i = 0; i < 4; ++i) {
    int r = rp + i * 32;          // even row; pair (r, r+1)
    v0[i] = *(const float4*)(src + (size_t)(r0 + r)     * C + c0 + tc);
    v1[i] = *(const float4*)(src + (size_t)(r0 + r + 1) * C + c0 + tc);
  }
#pragma unroll
  for (int i = 0; i < 4; ++i) {
    int r = rp + i * 32;
#pragma unroll
    for (int q = 0; q < 4; ++q) {
      int c = tc + q;
      int xorv = ((c >> 2) & 7) << 3;
      float a = ((const float*)&v0[i])[q];
      float b = ((const float*)&v1[i])[q];
      *(unsigned int*)&tileT[c][r ^ xorv] =
          (unsigned int)bfbits(a) | ((unsigned int)bfbits(b) << 16);
    }
  }
  __syncthreads();
  int tc2 = (tid & 15) * 8;       // row offset within column, 0..120
  int tr2 = tid >> 4;             // 0..15
#pragma unroll
  for (int i = 0; i < 4; ++i) {
    int c = tr2 + i * 16;         // 0..63
    int xorv = ((c >> 2) & 7) << 3;
    *(bf16x8*)(dst + (size_t)(c0 + c) * R + r0 + tc2) =
        *(const bf16x8*)&tileT[c][tc2 ^ xorv];
  }
}

// ======== prep: ONE launch = W1 transpose + W2 transpose + router ========
// blocks [0,2048)      : W1 [E][D][H] fp32 -> W1T [E][H][D] bf16  (32 c x 8 r x 8 e)
// blocks [2048,4096)   : W2 [E][H][D] fp32 -> W2T [E][D][H] bf16  (16 c x 16 r x 8 e)
// blocks [4096,4608)   : router (logits, top-2, gates, bf16 cast of x)
__global__ __launch_bounds__(256) void prep_kernel(
    const float* __restrict__ x,  const float* __restrict__ Wr,
    const float* __restrict__ br, const float* __restrict__ W1,
    const float* __restrict__ W2,
    int* __restrict__ topk_e, float* __restrict__ topk_g,
    bf16* __restrict__ xb, bf16* __restrict__ W1T, bf16* __restrict__ W2T) {
  __shared__ unsigned short tileT[64][136];   // 17.4 KB
  int b = blockIdx.x;
  if (b < 2048) {
    int bx = b & 31, by = (b >> 5) & 7, bz = b >> 8;
    const float* src = W1 + (size_t)bz * DDIM * HDIM;
    bf16* dst = W1T + (size_t)bz * DDIM * HDIM;
    transpose_tile128(src, dst, DDIM, HDIM, bx * 64, by * 128, tileT);
    return;
  }
  if (b < 4096) {
    int lb = b - 2048;
    int bx = lb & 15, by = (lb >> 4) & 15, bz = lb >> 8;
    const float* src = W2 + (size_t)bz * DDIM * HDIM;
    bf16* dst = W2T + (size_t)bz * DDIM * HDIM;
    transpose_tile128(src, dst, HDIM, DDIM, bx * 64, by * 128, tileT);
    return;
  }
  // ---- router: wave = 2 tokens; lane l owns channels d = l + 64*i ----
  int rb = b - 4096;                      // 0..511
  int wave = threadIdx.x >> 6;
  int lane = threadIdx.x & 63;
  int t0 = (rb * 4 + wave) * 2;

  float acc[16];
#pragma unroll
  for (int j = 0; j < 16; ++j) acc[j] = 0.f;

#pragma unroll
  for (int i = 0; i < DDIM / 64; ++i) {
    int d = i * 64 + lane;
    float4 w0 = *(const float4*)(Wr + (size_t)d * E);
    float4 w1 = *(const float4*)(Wr + (size_t)d * E + 4);
#pragma unroll
    for (int t = 0; t < 2; ++t) {
      float xv = x[(size_t)(t0 + t) * DDIM + d];
      xb[(size_t)(t0 + t) * DDIM + d] = (bf16)xv;
      acc[t * 8 + 0] += xv * w0.x; acc[t * 8 + 1] += xv * w0.y;
      acc[t * 8 + 2] += xv * w0.z; acc[t * 8 + 3] += xv * w0.w;
      acc[t * 8 + 4] += xv * w1.x; acc[t * 8 + 5] += xv * w1.y;
      acc[t * 8 + 6] += xv * w1.z; acc[t * 8 + 7] += xv * w1.w;
    }
  }
#pragma unroll
  for (int off = 32; off > 0; off >>= 1) {
#pragma unroll
    for (int j = 0; j < 16; ++j) acc[j] += __shfl_xor(acc[j], off, 64);
  }
  if (lane == 0) {
#pragma unroll
    for (int t = 0; t < 2; ++t) {
      int tt = t0 + t;
      float lg[E];
#pragma unroll
      for (int e = 0; e < E; ++e) lg[e] = acc[t * 8 + e] + br[e];
      int e0 = 0;
#pragma unroll
      for (int e = 1; e < E; ++e) if (lg[e] > lg[e0]) e0 = e;
      int e1 = (e0 == 0) ? 1 : 0;
#pragma unroll
      for (int e = 0; e < E; ++e) if (e != e0 && lg[e] > lg[e1]) e1 = e;
      float ex = expf(lg[e1] - lg[e0]);
      float s = 1.f + ex;
      topk_e[2 * tt]     = e0;
      topk_e[2 * tt + 1] = e1;
      topk_g[2 * tt]     = 1.f / s;
      topk_g[2 * tt + 1] = ex / s;
    }
  }
}

// ======== scan+scatter: single block, 1024 threads, FULLY PARALLEL bookkeeping ========
// Round-6 post-mortem: this kernel was 99us -- thread-0 serial section used a
// runtime-indexed live[] array (scratch, rule #20) + ~70 serial dependent global
// round-trips. Now: every thread computes the 8-expert prefixes locally in
// registers (static unroll); threads 0..55 derive + write one blockmap slot each;
// threads 0..8 write counts/offsets/cursors. One parallel wave of writes.
__global__ __launch_bounds__(1024) void scan_scatter_kernel(
    const int* __restrict__ topk_e,
    int* __restrict__ counts,    // stride 16 ints per expert
    int* __restrict__ offsets,
    int* __restrict__ blockmap,  // [MAXBLK] packed e<<16|mtile, -1 = ghost
    int* __restrict__ rowtok, int* __restrict__ tokrow) {
  __shared__ int hist[E], curs[E];
  int tid = threadIdx.x;
  int lane = tid & 63;
  unsigned long long lt = ((unsigned long long)1 << lane) - 1;
  if (tid < E) hist[tid] = 0;
  __syncthreads();
  // pass 1: ballot-aggregated histogram (8 grid-stride iterations)
  for (int i = tid; i < 2 * NTOK; i += 1024) {
    int e = topk_e[i];
#pragma unroll
    for (int ee = 0; ee < E; ++ee) {
      unsigned long long m = __ballot(e == ee);
      if (m && lane == __ffsll((long long)m) - 1) atomicAdd(&hist[ee], __popcll(m));
    }
  }
  __syncthreads();
  // parallel scan + balanced blockmap (all in registers, static indexing only)
  int h[E], pre[E + 1], nt[E], tb[E + 1];
  pre[0] = 0; tb[0] = 0;
#pragma unroll
  for (int e = 0; e < E; ++e) {
    h[e] = hist[e];
    pre[e + 1] = pre[e] + h[e];
    nt[e] = (h[e] + 191) / 192;
    tb[e + 1] = tb[e] + nt[e];
  }
  int nb = tb[E];
  if (tid < E) { counts[tid * 16] = h[tid]; curs[tid] = pre[tid]; }
  if (tid < E + 1) offsets[tid] = pre[tid];
  if (tid < MAXBLK) {
    int xc = tid / 7, j = tid % 7;   // chunk, slot
    int lo = (nb * xc) >> 3, hi = (nb * (xc + 1)) >> 3;
    int idx = lo + j, v = -1;
    if (idx < hi) {
      int e = 0;
#pragma unroll
      for (int k = 1; k < E; ++k) if (idx >= tb[k]) e = k;
      v = (e << 16) | (idx - tb[e]);
    }
    blockmap[tid] = v;
  }
  __syncthreads();
  // pass 2: ballot-aggregated LDS-cursor scatter
  for (int i = tid; i < 2 * NTOK; i += 1024) {
    int e = topk_e[i];
#pragma unroll
    for (int ee = 0; ee < E; ++ee) {
      unsigned long long m = __ballot(e == ee);
      if (m) {
        int leader = __ffsll((long long)m) - 1;
        int base = 0;
        if (lane == leader) base = atomicAdd(&curs[ee], __popcll(m));
        base = __shfl(base, leader, 64);
        if (e == ee) {
          int row = base + __popcll(m & lt);
          rowtok[row] = i >> 1;
          tokrow[i] = row;
        }
      }
    }
  }
}

// ======== grouped FFN GEMM: 192x128 tile, BK=64, double-buffer, counted vmcnt(10) ======
// (unchanged from round 6 -- best measured: 74.7/72us, 0 conflicts, FETCH ~36MB)
template <bool GATHER, bool RELU>
__global__ __launch_bounds__(256, 2) void ffn_gemm(
    const bf16* __restrict__ A, const bf16* __restrict__ W,
    const float* __restrict__ bias, bf16* __restrict__ Y,
    const int* __restrict__ rowtok, const int* __restrict__ offsets,
    const int* __restrict__ counts,   // stride 16
    const int* __restrict__ blockmap,
    int Kdim, int Ndim) {
  static_assert(MAXBLK == 56, "XCD chunking assumes gridDim.x == 56 == 8*7");
  int xcd = blockIdx.x & 7;           // 56 % 8 == 0
  int mq  = blockIdx.x >> 3;          // 0..6 slot within chunk
  int bm = blockmap[xcd * 7 + mq];
  if (bm < 0) return;                 // balanced ghosts
  int e = bm >> 16;
  int mBase = (bm & 0xffff) * 192;
  int cnt = counts[e * 16];
  int rowBase = offsets[e] + mBase;
  int nBase = blockIdx.y * 128;
  int validRows = cnt - mBase; if (validRows > 192) validRows = 192;

  __shared__ bf16 Asm[2][192 * 64];   // 24 KB per buf
  __shared__ bf16 Bsm[2][128 * 64];   // 16 KB per buf  (total 80 KB -> 2 blocks/CU)

  int tid = threadIdx.x;
  int wave = tid >> 6, lane = tid & 63;
  int lrow = lane >> 3;     // 0..7  row within 8-row chunk
  int lseg = lane & 7;      // 16B segment within 128B row
  int sseg = lseg ^ lrow;   // T2: pre-swizzled SOURCE segment (LDS dest linear)

  const bf16* aptr[6];
  const bf16* bptr[4];
#pragma unroll
  for (int i = 0; i < 6; ++i) {
    int c = wave + i * 4;             // 0..23 A row-chunks
    int r = rowBase + c * 8 + lrow;
    if (r > MAXROWS - 1) r = MAXROWS - 1;   // partial tile: harmless dup, masked at store
    size_t rowoff = GATHER ? (size_t)rowtok[r] * Kdim : (size_t)r * Kdim;
    aptr[i] = A + rowoff + sseg * 8;
  }
#pragma unroll
  for (int i = 0; i < 4; ++i) {
    int c = wave + i * 4;             // 0..15 B row-chunks
    bptr[i] = W + ((size_t)e * Ndim + nBase + c * 8 + lrow) * (size_t)Kdim + sseg * 8;
  }

  floatx4 acc[6][4];
#pragma unroll
  for (int m = 0; m < 6; ++m)
#pragma unroll
    for (int n = 0; n < 4; ++n) acc[m][n] = floatx4{0.f, 0.f, 0.f, 0.f};

  int wm = wave & 1, wn = wave >> 1;  // wave grid: 2m x 2n; per wave 96 x 64 output
  int mrow = lane & 15;
  int kseg0 = lane >> 4;    // 0..3
  int swz = mrow & 7;       // T2 read-side XOR

  auto issue = [&](int p, int kc) {   // 10 loads per wave (6 A + 4 B)
#pragma unroll
    for (int i = 0; i < 6; ++i) {
      int c = wave + i * 4;
      gload_lds16(aptr[i] + kc, &Asm[p][c * 512]);
    }
#pragma unroll
    for (int i = 0; i < 4; ++i) {
      int c = wave + i * 4;
      gload_lds16(bptr[i] + kc, &Bsm[p][c * 512]);
    }
  };

  issue(0, 0);
  int p = 0;
  for (int kc = 0; kc < Kdim; kc += 64) {
    if (kc + 64 < Kdim) {
      issue(p ^ 1, kc + 64);
      asm volatile("s_waitcnt vmcnt(10)" ::: "memory");  // tile t done; next in flight
    } else {
      asm volatile("s_waitcnt vmcnt(0)" ::: "memory");
    }
    asm volatile("s_barrier" ::: "memory");

#pragma unroll
    for (int ks = 0; ks < 2; ++ks) {
      int kk = (((ks << 2) | kseg0) ^ swz) << 3;   // element offset within 64-wide row
      bf16x8 af[6], bfr[4];
#pragma unroll
      for (int m = 0; m < 6; ++m)
        af[m] = ds_read16(&Asm[p][(wm * 96 + m * 16 + mrow) * 64 + kk]);
#pragma unroll
      for (int n = 0; n < 4; ++n)
        bfr[n] = ds_read16(&Bsm[p][(wn * 64 + n * 16 + mrow) * 64 + kk]);
      asm volatile("s_waitcnt lgkmcnt(0)" ::: "memory");
      __builtin_amdgcn_sched_barrier(0);   // rule #18: MFMAs stay below the lgkm wait
      __builtin_amdgcn_s_setprio(1);
#pragma unroll
      for (int m = 0; m < 6; ++m)
#pragma unroll
        for (int n = 0; n < 4; ++n)
          acc[m][n] = __builtin_amdgcn_mfma_f32_16x16x32_bf16(af[m], bfr[n], acc[m][n], 0, 0, 0);
      __builtin_amdgcn_s_setprio(0);
    }

    asm volatile("s_barrier" ::: "memory");   // all waves' reads of buf p done
    p ^= 1;
  }

  // epilogue: C/D layout col=lane&15, row=(lane>>4)*4+reg  [m89-verified]
  int crow = (lane >> 4) * 4;
  int ccol = lane & 15;
#pragma unroll
  for (int n = 0; n < 4; ++n) {
    int colg = nBase + wn * 64 + n * 16 + ccol;
    float bv = bias[(size_t)e * Ndim + colg];
#pragma unroll
    for (int m = 0; m < 6; ++m) {
#pragma unroll
      for (int r = 0; r < 4; ++r) {
        int rl = wm * 96 + m * 16 + crow + r;
        if (rl < validRows) {
          float v = acc[m][n][r] + bv;
          if (RELU) v = fmaxf(v, 0.f);
          Y[(size_t)(rowBase + rl) * Ndim + colg] = (bf16)v;
        }
      }
    }
  }
}

// ---------------- combine: out[t] = g0*Y2[r0] + g1*Y2[r1]  (fp32 out) ----------------
__global__ void combine_kernel(const bf16* __restrict__ Y2,
                               const int* __restrict__ tokrow,
                               const float* __restrict__ topk_g,
                               float* __restrict__ out) {
  int idx = blockIdx.x * 256 + threadIdx.x;
  int t = idx >> 7;              // DDIM/8 = 128 vectors per token
  int d8 = (idx & 127) * 8;
  int r0 = tokrow[2 * t], r1 = tokrow[2 * t + 1];
  float g0 = topk_g[2 * t], g1 = topk_g[2 * t + 1];
  bf16x8 a = *(const bf16x8*)(Y2 + (size_t)r0 * DDIM + d8);
  bf16x8 b = *(const bf16x8*)(Y2 + (size_t)r1 * DDIM + d8);
  float o[8];
#pragma unroll
  for (int j = 0; j < 8; ++j) o[j] = g0 * (float)a[j] + g1 * (float)b[j];
  float* op = out + (size_t)t * DDIM + d8;
  *(float4*)op = *(float4*)&o[0];
  *(float4*)(op + 4) = *(float4*)&o[4];
}

}  // namespace

extern "C" void kernel_launch(void* const* d_in, const int* in_sizes, int n_in,
                              void* d_out, int out_size, void* d_ws, size_t ws_size,
                              hipStream_t stream) {
  const float* x  = (const float*)d_in[0];   // [B,T,D] fp32
  const float* Wr = (const float*)d_in[1];   // [D,E]   fp32
  const float* br = (const float*)d_in[2];   // [E]     fp32
  const float* W1 = (const float*)d_in[3];   // [E,D,H] fp32
  const float* b1 = (const float*)d_in[4];   // [E,H]   fp32
  const float* W2 = (const float*)d_in[5];   // [E,H,D] fp32
  const float* b2 = (const float*)d_in[6];   // [E,D]   fp32
  float* out = (float*)d_out;                // [B,T,D] fp32

  char* w = (char*)d_ws;
  int*   counts   = (int*)(w);               // 8 experts, stride 16 ints (64B apart)
  int*   offsets  = (int*)(w + 1024);        // 9 ints
  int*   blockmap = (int*)(w + 2048);        // 56 ints
  int*   topk_e   = (int*)(w + 4096);
  float* topk_g   = (float*)(w + 4096 + 32768);
  int*   rowtok   = (int*)(w + 4096 + 65536);
  int*   tokrow   = (int*)(w + 4096 + 98304);
  char*  big      = w + 4096 + 131072;
  bf16* xb  = (bf16*)(big);                        // [4096][D]  bf16   8.4 MB
  bf16* W1T = (bf16*)(big + 8388608);              // [E][H][D]  bf16  33.5 MB
  bf16* W2T = (bf16*)(big + 8388608 + 33554432);   // [E][D][H]  bf16  33.5 MB
  bf16* Y1  = (bf16*)(big + 8388608 + 67108864);   // [8192][H]  bf16  33.5 MB
  bf16* Y2  = (bf16*)(big + 8388608);              // alias W1T (dead after GEMM1)

  // 5 launches: prep(transposes+router) -> scan_scatter -> 2x GEMM -> combine
  prep_kernel<<<4608, 256, 0, stream>>>(x, Wr, br, W1, W2, topk_e, topk_g, xb, W1T, W2T);
  scan_scatter_kernel<<<1, 1024, 0, stream>>>(topk_e, counts, offsets, blockmap,
                                              rowtok, tokrow);
  ffn_gemm<true, true><<<dim3(MAXBLK, HDIM / 128), 256, 0, stream>>>(
      xb, W1T, b1, Y1, rowtok, offsets, counts, blockmap, DDIM, HDIM);
  ffn_gemm<false, false><<<dim3(MAXBLK, DDIM / 128), 256, 0, stream>>>(
      Y1, W2T, b2, Y2, rowtok, offsets, counts, blockmap, HDIM, DDIM);
  combine_kernel<<<NTOK * DDIM / 8 / 256, 256, 0, stream>>>(Y2, tokrow, topk_g, out);
}

// Round 8
// 319.934 us; speedup vs baseline: 1.2614x; 1.0301x over previous
//
#include <hip/hip_runtime.h>
#include <hip/hip_bf16.h>
#include <math.h>

namespace {

constexpr int NTOK   = 4096;   // B*T
constexpr int DDIM   = 1024;
constexpr int E      = 8;
constexpr int HDIM   = 2048;
constexpr int MAXROWS = 8192;  // NTOK * K (every token -> exactly 2 rows)
constexpr int MAXBLK  = 56;    // 8 XCD chunks x 7 slots (>= sum_e ceil(cnt_e/192) <= 50)

typedef __bf16 bf16;
typedef __attribute__((ext_vector_type(8))) __bf16 bf16x8;
typedef __attribute__((ext_vector_type(4))) float floatx4;
typedef __attribute__((ext_vector_type(4))) int   i32x4;

// async global->LDS, 16B per lane; LDS dest = WAVE-UNIFORM base, HW adds lane*16
__device__ inline void gload_lds16(const bf16* g, bf16* l) {
  __builtin_amdgcn_global_load_lds(
      (const __attribute__((address_space(1))) void*)g,
      (__attribute__((address_space(3))) void*)l, 16, 0, 0);
}

// inline-asm ds_read_b128: invisible to the waitcnt pass (no conservative vmcnt(0)
// drain of in-flight prefetch). Discipline: explicit lgkmcnt(0) + sched_barrier(0)
// before the consuming MFMAs (rule #18).
__device__ inline bf16x8 ds_read16(const bf16* p) {
  i32x4 r;
  asm volatile("ds_read_b128 %0, %1"
               : "=v"(r)
               : "v"((const __attribute__((address_space(3))) bf16*)p));
  return __builtin_bit_cast(bf16x8, r);
}

__device__ inline unsigned short bfbits(float f) {
  return __builtin_bit_cast(unsigned short, (bf16)f);
}

// -------- transpose+cast tile: 128 rows x 64 cols; fp32 [R][C] -> bf16 [C][R] --------
// LDS tileT[c][r] with XOR granule swizzle r_phys = r ^ (((c>>2)&7)<<3): write side
// 2-way banks (free); read side XOR is uniform per instruction. Loads staged in
// static-indexed float4 arrays so all 8 stay in flight (rule #20).
__device__ inline void transpose_tile128(const float* __restrict__ src,
                                         bf16* __restrict__ dst,
                                         int R, int C, int c0, int r0,
                                         unsigned short (*tileT)[136]) {
  int tid = threadIdx.x;
  int rp = (tid >> 4) * 2;        // 0,2,...,30
  int tc = (tid & 15) * 4;        // 0..60
  float4 v0[4], v1[4];
#pragma unroll
  for (int i = 0; i < 4; ++i) {
    int r = rp + i * 32;          // even row; pair (r, r+1)
    v0[i] = *(const float4*)(src + (size_t)(r0 + r)     * C + c0 + tc);
    v1[i] = *(const float4*)(src + (size_t)(r0 + r + 1) * C + c0 + tc);
  }
#pragma unroll
  for (int i = 0; i < 4; ++i) {
    int r = rp + i * 32;
#pragma unroll
    for (int q = 0; q < 4; ++q) {
      int c = tc + q;
      int xorv = ((c >> 2) & 7) << 3;
      float a = ((const float*)&v0[i])[q];
      float b = ((const float*)&v1[i])[q];
      *(unsigned int*)&tileT[c][r ^ xorv] =
          (unsigned int)bfbits(a) | ((unsigned int)bfbits(b) << 16);
    }
  }
  __syncthreads();
  int tc2 = (tid & 15) * 8;       // row offset within column, 0..120
  int tr2 = tid >> 4;             // 0..15
#pragma unroll
  for (int i = 0; i < 4; ++i) {
    int c = tr2 + i * 16;         // 0..63
    int xorv = ((c >> 2) & 7) << 3;
    *(bf16x8*)(dst + (size_t)(c0 + c) * R + r0 + tc2) =
        *(const bf16x8*)&tileT[c][tc2 ^ xorv];
  }
}

// ======== prep: router + W1 transpose ONLY (W2 transpose rides inside GEMM1 launch) ====
// blocks [0,2048)      : W1 [E][D][H] fp32 -> W1T [E][H][D] bf16  (32 c x 8 r x 8 e)
// blocks [2048,2560)   : router (logits, top-2, gates, bf16 cast of x)
__global__ __launch_bounds__(256) void prep_kernel(
    const float* __restrict__ x,  const float* __restrict__ Wr,
    const float* __restrict__ br, const float* __restrict__ W1,
    int* __restrict__ topk_e, float* __restrict__ topk_g,
    bf16* __restrict__ xb, bf16* __restrict__ W1T) {
  __shared__ unsigned short tileT[64][136];   // 17.4 KB
  int b = blockIdx.x;
  if (b < 2048) {
    int bx = b & 31, by = (b >> 5) & 7, bz = b >> 8;
    const float* src = W1 + (size_t)bz * DDIM * HDIM;
    bf16* dst = W1T + (size_t)bz * DDIM * HDIM;
    transpose_tile128(src, dst, DDIM, HDIM, bx * 64, by * 128, tileT);
    return;
  }
  // ---- router: wave = 2 tokens; lane l owns channels d = l + 64*i ----
  int rb = b - 2048;                      // 0..511
  int wave = threadIdx.x >> 6;
  int lane = threadIdx.x & 63;
  int t0 = (rb * 4 + wave) * 2;

  float acc[16];
#pragma unroll
  for (int j = 0; j < 16; ++j) acc[j] = 0.f;

#pragma unroll
  for (int i = 0; i < DDIM / 64; ++i) {
    int d = i * 64 + lane;
    float4 w0 = *(const float4*)(Wr + (size_t)d * E);
    float4 w1 = *(const float4*)(Wr + (size_t)d * E + 4);
#pragma unroll
    for (int t = 0; t < 2; ++t) {
      float xv = x[(size_t)(t0 + t) * DDIM + d];
      xb[(size_t)(t0 + t) * DDIM + d] = (bf16)xv;
      acc[t * 8 + 0] += xv * w0.x; acc[t * 8 + 1] += xv * w0.y;
      acc[t * 8 + 2] += xv * w0.z; acc[t * 8 + 3] += xv * w0.w;
      acc[t * 8 + 4] += xv * w1.x; acc[t * 8 + 5] += xv * w1.y;
      acc[t * 8 + 6] += xv * w1.z; acc[t * 8 + 7] += xv * w1.w;
    }
  }
#pragma unroll
  for (int off = 32; off > 0; off >>= 1) {
#pragma unroll
    for (int j = 0; j < 16; ++j) acc[j] += __shfl_xor(acc[j], off, 64);
  }
  if (lane == 0) {
#pragma unroll
    for (int t = 0; t < 2; ++t) {
      int tt = t0 + t;
      float lg[E];
#pragma unroll
      for (int e = 0; e < E; ++e) lg[e] = acc[t * 8 + e] + br[e];
      int e0 = 0;
#pragma unroll
      for (int e = 1; e < E; ++e) if (lg[e] > lg[e0]) e0 = e;
      int e1 = (e0 == 0) ? 1 : 0;
#pragma unroll
      for (int e = 0; e < E; ++e) if (e != e0 && lg[e] > lg[e1]) e1 = e;
      float ex = expf(lg[e1] - lg[e0]);
      float s = 1.f + ex;
      topk_e[2 * tt]     = e0;
      topk_e[2 * tt + 1] = e1;
      topk_g[2 * tt]     = 1.f / s;
      topk_g[2 * tt + 1] = ex / s;
    }
  }
}

// ======== scan+scatter: single block, 1024 threads, fully parallel bookkeeping ========
__global__ __launch_bounds__(1024) void scan_scatter_kernel(
    const int* __restrict__ topk_e,
    int* __restrict__ counts,    // stride 16 ints per expert
    int* __restrict__ offsets,
    int* __restrict__ blockmap,  // [MAXBLK] packed e<<16|mtile, -1 = ghost
    int* __restrict__ rowtok, int* __restrict__ tokrow) {
  __shared__ int hist[E], curs[E];
  int tid = threadIdx.x;
  int lane = tid & 63;
  unsigned long long lt = ((unsigned long long)1 << lane) - 1;
  if (tid < E) hist[tid] = 0;
  __syncthreads();
  for (int i = tid; i < 2 * NTOK; i += 1024) {
    int e = topk_e[i];
#pragma unroll
    for (int ee = 0; ee < E; ++ee) {
      unsigned long long m = __ballot(e == ee);
      if (m && lane == __ffsll((long long)m) - 1) atomicAdd(&hist[ee], __popcll(m));
    }
  }
  __syncthreads();
  int h[E], pre[E + 1], nt[E], tb[E + 1];
  pre[0] = 0; tb[0] = 0;
#pragma unroll
  for (int e = 0; e < E; ++e) {
    h[e] = hist[e];
    pre[e + 1] = pre[e] + h[e];
    nt[e] = (h[e] + 191) / 192;
    tb[e + 1] = tb[e] + nt[e];
  }
  int nb = tb[E];
  if (tid < E) { counts[tid * 16] = h[tid]; curs[tid] = pre[tid]; }
  if (tid < E + 1) offsets[tid] = pre[tid];
  if (tid < MAXBLK) {
    int xc = tid / 7, j = tid % 7;   // chunk, slot
    int lo = (nb * xc) >> 3, hi = (nb * (xc + 1)) >> 3;
    int idx = lo + j, v = -1;
    if (idx < hi) {
      int e = 0;
#pragma unroll
      for (int k = 1; k < E; ++k) if (idx >= tb[k]) e = k;
      v = (e << 16) | (idx - tb[e]);
    }
    blockmap[tid] = v;
  }
  __syncthreads();
  for (int i = tid; i < 2 * NTOK; i += 1024) {
    int e = topk_e[i];
#pragma unroll
    for (int ee = 0; ee < E; ++ee) {
      unsigned long long m = __ballot(e == ee);
      if (m) {
        int leader = __ffsll((long long)m) - 1;
        int base = 0;
        if (lane == leader) base = atomicAdd(&curs[ee], __popcll(m));
        base = __shfl(base, leader, 64);
        if (e == ee) {
          int row = base + __popcll(m & lt);
          rowtok[row] = i >> 1;
          tokrow[i] = row;
        }
      }
    }
  }
}

// ======== grouped FFN GEMM: 192x128 tile, BK=64, dbuf, counted vmcnt(10) ========
// Inner loop unchanged (best measured). NEW: trailing grid-y layers carry the W2
// transpose (GEMM1 launch only): no dependency either way with GEMM1 -> correctness
// is dispatch-order independent (G16); trailing linear IDs fill CU slots as GEMM
// blocks retire, streaming W2 on GEMM1's idle HBM (<17% used).
template <bool GATHER, bool RELU>
__global__ __launch_bounds__(256, 2) void ffn_gemm(
    const bf16* __restrict__ A, const bf16* __restrict__ W,
    const float* __restrict__ bias, bf16* __restrict__ Y,
    const int* __restrict__ rowtok, const int* __restrict__ offsets,
    const int* __restrict__ counts,   // stride 16
    const int* __restrict__ blockmap,
    const float* __restrict__ Tsrc, bf16* __restrict__ Tdst, int ntr,
    int Kdim, int Ndim) {
  static_assert(MAXBLK == 56, "XCD chunking assumes gridDim.x == 56 == 8*7");
  __shared__ bf16 Asm[2][192 * 64];   // 24 KB per buf
  __shared__ bf16 Bsm[2][128 * 64];   // 16 KB per buf  (total 80 KB -> 2 blocks/CU)

  int NY = Ndim >> 7;
  if ((int)blockIdx.y >= NY) {
    // ---- piggybacked W2 transpose tile: [E][H][D] fp32 -> [E][D][H] bf16 ----
    int tb = ((int)blockIdx.y - NY) * (int)gridDim.x + (int)blockIdx.x;
    if (tb < ntr) {
      int bx = tb & 15, by2 = (tb >> 4) & 15, bz = tb >> 8;
      auto tileT = (unsigned short(*)[136])(&Asm[0][0]);
      transpose_tile128(Tsrc + (size_t)bz * DDIM * HDIM,
                        Tdst + (size_t)bz * DDIM * HDIM,
                        HDIM, DDIM, bx * 64, by2 * 128, tileT);
    }
    return;
  }

  int xcd = blockIdx.x & 7;           // 56 % 8 == 0
  int mq  = blockIdx.x >> 3;          // 0..6 slot within chunk
  int bm = blockmap[xcd * 7 + mq];
  if (bm < 0) return;                 // balanced ghosts
  int e = bm >> 16;
  int mBase = (bm & 0xffff) * 192;
  int cnt = counts[e * 16];
  int rowBase = offsets[e] + mBase;
  int nBase = blockIdx.y * 128;
  int validRows = cnt - mBase; if (validRows > 192) validRows = 192;

  int tid = threadIdx.x;
  int wave = tid >> 6, lane = tid & 63;
  int lrow = lane >> 3;     // 0..7  row within 8-row chunk
  int lseg = lane & 7;      // 16B segment within 128B row
  int sseg = lseg ^ lrow;   // T2: pre-swizzled SOURCE segment (LDS dest linear)

  const bf16* aptr[6];
  const bf16* bptr[4];
#pragma unroll
  for (int i = 0; i < 6; ++i) {
    int c = wave + i * 4;             // 0..23 A row-chunks
    int r = rowBase + c * 8 + lrow;
    if (r > MAXROWS - 1) r = MAXROWS - 1;   // partial tile: harmless dup, masked at store
    size_t rowoff = GATHER ? (size_t)rowtok[r] * Kdim : (size_t)r * Kdim;
    aptr[i] = A + rowoff + sseg * 8;
  }
#pragma unroll
  for (int i = 0; i < 4; ++i) {
    int c = wave + i * 4;             // 0..15 B row-chunks
    bptr[i] = W + ((size_t)e * Ndim + nBase + c * 8 + lrow) * (size_t)Kdim + sseg * 8;
  }

  floatx4 acc[6][4];
#pragma unroll
  for (int m = 0; m < 6; ++m)
#pragma unroll
    for (int n = 0; n < 4; ++n) acc[m][n] = floatx4{0.f, 0.f, 0.f, 0.f};

  int wm = wave & 1, wn = wave >> 1;  // wave grid: 2m x 2n; per wave 96 x 64 output
  int mrow = lane & 15;
  int kseg0 = lane >> 4;    // 0..3
  int swz = mrow & 7;       // T2 read-side XOR

  auto issue = [&](int p, int kc) {   // 10 loads per wave (6 A + 4 B)
#pragma unroll
    for (int i = 0; i < 6; ++i) {
      int c = wave + i * 4;
      gload_lds16(aptr[i] + kc, &Asm[p][c * 512]);
    }
#pragma unroll
    for (int i = 0; i < 4; ++i) {
      int c = wave + i * 4;
      gload_lds16(bptr[i] + kc, &Bsm[p][c * 512]);
    }
  };

  issue(0, 0);
  int p = 0;
  for (int kc = 0; kc < Kdim; kc += 64) {
    if (kc + 64 < Kdim) {
      issue(p ^ 1, kc + 64);
      asm volatile("s_waitcnt vmcnt(10)" ::: "memory");  // tile t done; next in flight
    } else {
      asm volatile("s_waitcnt vmcnt(0)" ::: "memory");
    }
    asm volatile("s_barrier" ::: "memory");

#pragma unroll
    for (int ks = 0; ks < 2; ++ks) {
      int kk = (((ks << 2) | kseg0) ^ swz) << 3;   // element offset within 64-wide row
      bf16x8 af[6], bfr[4];
#pragma unroll
      for (int m = 0; m < 6; ++m)
        af[m] = ds_read16(&Asm[p][(wm * 96 + m * 16 + mrow) * 64 + kk]);
#pragma unroll
      for (int n = 0; n < 4; ++n)
        bfr[n] = ds_read16(&Bsm[p][(wn * 64 + n * 16 + mrow) * 64 + kk]);
      asm volatile("s_waitcnt lgkmcnt(0)" ::: "memory");
      __builtin_amdgcn_sched_barrier(0);   // rule #18: MFMAs stay below the lgkm wait
      __builtin_amdgcn_s_setprio(1);
#pragma unroll
      for (int m = 0; m < 6; ++m)
#pragma unroll
        for (int n = 0; n < 4; ++n)
          acc[m][n] = __builtin_amdgcn_mfma_f32_16x16x32_bf16(af[m], bfr[n], acc[m][n], 0, 0, 0);
      __builtin_amdgcn_s_setprio(0);
    }

    asm volatile("s_barrier" ::: "memory");   // all waves' reads of buf p done
    p ^= 1;
  }

  // epilogue: C/D layout col=lane&15, row=(lane>>4)*4+reg  [m89-verified]
  int crow = (lane >> 4) * 4;
  int ccol = lane & 15;
#pragma unroll
  for (int n = 0; n < 4; ++n) {
    int colg = nBase + wn * 64 + n * 16 + ccol;
    float bv = bias[(size_t)e * Ndim + colg];
#pragma unroll
    for (int m = 0; m < 6; ++m) {
#pragma unroll
      for (int r = 0; r < 4; ++r) {
        int rl = wm * 96 + m * 16 + crow + r;
        if (rl < validRows) {
          float v = acc[m][n][r] + bv;
          if (RELU) v = fmaxf(v, 0.f);
          Y[(size_t)(rowBase + rl) * Ndim + colg] = (bf16)v;
        }
      }
    }
  }
}

// ---------------- combine: out[t] = g0*Y2[r0] + g1*Y2[r1]  (fp32 out) ----------------
__global__ void combine_kernel(const bf16* __restrict__ Y2,
                               const int* __restrict__ tokrow,
                               const float* __restrict__ topk_g,
                               float* __restrict__ out) {
  int idx = blockIdx.x * 256 + threadIdx.x;
  int t = idx >> 7;              // DDIM/8 = 128 vectors per token
  int d8 = (idx & 127) * 8;
  int r0 = tokrow[2 * t], r1 = tokrow[2 * t + 1];
  float g0 = topk_g[2 * t], g1 = topk_g[2 * t + 1];
  bf16x8 a = *(const bf16x8*)(Y2 + (size_t)r0 * DDIM + d8);
  bf16x8 b = *(const bf16x8*)(Y2 + (size_t)r1 * DDIM + d8);
  float o[8];
#pragma unroll
  for (int j = 0; j < 8; ++j) o[j] = g0 * (float)a[j] + g1 * (float)b[j];
  float* op = out + (size_t)t * DDIM + d8;
  *(float4*)op = *(float4*)&o[0];
  *(float4*)(op + 4) = *(float4*)&o[4];
}

}  // namespace

extern "C" void kernel_launch(void* const* d_in, const int* in_sizes, int n_in,
                              void* d_out, int out_size, void* d_ws, size_t ws_size,
                              hipStream_t stream) {
  const float* x  = (const float*)d_in[0];   // [B,T,D] fp32
  const float* Wr = (const float*)d_in[1];   // [D,E]   fp32
  const float* br = (const float*)d_in[2];   // [E]     fp32
  const float* W1 = (const float*)d_in[3];   // [E,D,H] fp32
  const float* b1 = (const float*)d_in[4];   // [E,H]   fp32
  const float* W2 = (const float*)d_in[5];   // [E,H,D] fp32
  const float* b2 = (const float*)d_in[6];   // [E,D]   fp32
  float* out = (float*)d_out;                // [B,T,D] fp32

  char* w = (char*)d_ws;
  int*   counts   = (int*)(w);               // 8 experts, stride 16 ints (64B apart)
  int*   offsets  = (int*)(w + 1024);        // 9 ints
  int*   blockmap = (int*)(w + 2048);        // 56 ints
  int*   topk_e   = (int*)(w + 4096);
  float* topk_g   = (float*)(w + 4096 + 32768);
  int*   rowtok   = (int*)(w + 4096 + 65536);
  int*   tokrow   = (int*)(w + 4096 + 98304);
  char*  big      = w + 4096 + 131072;
  bf16* xb  = (bf16*)(big);                        // [4096][D]  bf16   8.4 MB
  bf16* W1T = (bf16*)(big + 8388608);              // [E][H][D]  bf16  33.5 MB
  bf16* W2T = (bf16*)(big + 8388608 + 33554432);   // [E][D][H]  bf16  33.5 MB
  bf16* Y1  = (bf16*)(big + 8388608 + 67108864);   // [8192][H]  bf16  33.5 MB
  bf16* Y2  = (bf16*)(big + 8388608);              // alias W1T (dead after GEMM1)

  // 4 launches: prep(router+W1T) -> scan_scatter -> GEMM1(+W2T piggyback) -> GEMM2 -> combine
  prep_kernel<<<2560, 256, 0, stream>>>(x, Wr, br, W1, topk_e, topk_g, xb, W1T);
  scan_scatter_kernel<<<1, 1024, 0, stream>>>(topk_e, counts, offsets, blockmap,
                                              rowtok, tokrow);
  // GEMM1 grid: 16 n-layers + 37 trailing layers carrying 2048 W2-transpose tiles
  ffn_gemm<true, true><<<dim3(MAXBLK, HDIM / 128 + 37), 256, 0, stream>>>(
      xb, W1T, b1, Y1, rowtok, offsets, counts, blockmap,
      W2, W2T, 2048, DDIM, HDIM);
  ffn_gemm<false, false><<<dim3(MAXBLK, DDIM / 128), 256, 0, stream>>>(
      Y1, W2T, b2, Y2, rowtok, offsets, counts, blockmap,
      nullptr, nullptr, 0, HDIM, DDIM);
  combine_kernel<<<NTOK * DDIM / 8 / 256, 256, 0, stream>>>(Y2, tokrow, topk_g, out);
}